// Round 2
// baseline (652.339 us; speedup 1.0000x reference)
//
#include <hip/hip_runtime.h>
#include <hip/hip_bf16.h>

#define BN_ 20000
#define D_ 128
#define FF_ 512
#define E_ 320000
#define NBLK 313   // ceil(20000/64)

// ---------------- small utility kernels ----------------

__global__ __launch_bounds__(256) void k_copy4(const float4* __restrict__ in,
                                               float4* __restrict__ out, int n4) {
    int i = blockIdx.x * 256 + threadIdx.x;
    if (i < n4) out[i] = in[i];
}

// Wcat[l][d][h*16+k] = Wv[l][h][d][k]   (3*128*128 = 49152 elements)
__global__ __launch_bounds__(256) void k_wcat(const float* __restrict__ Wv,
                                              float* __restrict__ Wcat) {
    int idx = blockIdx.x * 256 + threadIdx.x;
    if (idx >= 3 * 128 * 128) return;
    int l = idx / 16384, r = idx % 16384;
    int d = r >> 7, c = r & 127, h = c >> 4, k = c & 15;
    Wcat[idx] = Wv[((l * 8 + h) * 128 + d) * 16 + k];
}

__global__ __launch_bounds__(256) void k_zero(float* __restrict__ p, int n) {
    int i = blockIdx.x * 256 + threadIdx.x;
    if (i < n) p[i] = 0.f;
}

__global__ __launch_bounds__(256) void k_flag(const int* __restrict__ dst,
                                              float* __restrict__ flag) {
    int e = blockIdx.x * 256 + threadIdx.x;
    if (e < E_) flag[dst[e]] = 1.0f;
}

// ---------------- BatchNorm stats ----------------
__global__ __launch_bounds__(256) void k_stats(const float* __restrict__ Hx,
                                               float* __restrict__ part) {
    __shared__ float sS[256], sQ[256];
    int tid = threadIdx.x, b = blockIdx.x;
    int col = tid & 127, half = tid >> 7;
    int r0 = b * 100;
    float s = 0.f, q = 0.f;
    for (int r = half; r < 100; r += 2) {
        float v = Hx[(r0 + r) * D_ + col];
        s += v; q += v * v;
    }
    sS[tid] = s; sQ[tid] = q;
    __syncthreads();
    if (tid < 128) {
        part[b * 128 + tid]              = sS[tid] + sS[tid + 128];
        part[200 * 128 + b * 128 + tid]  = sQ[tid] + sQ[tid + 128];
    }
}

__global__ __launch_bounds__(128) void k_bnfin(const float* __restrict__ part,
                                               const float* __restrict__ w,
                                               const float* __restrict__ bb,
                                               float* __restrict__ ss) {
    int c = threadIdx.x;  // 128 threads
    float s = 0.f, q = 0.f;
    for (int i = 0; i < 200; ++i) {
        s += part[i * 128 + c];
        q += part[200 * 128 + i * 128 + c];
    }
    float mu  = s * (1.f / 20000.f);
    float var = q * (1.f / 20000.f) - mu * mu;
    var = fmaxf(var, 0.f);
    float rstd  = rsqrtf(var + 1e-5f);
    float scale = w[c] * rstd;
    ss[c]       = scale;
    ss[128 + c] = bb[c] - mu * scale;
}

// ---------------- GEMM kernels (MT=64, NT=128, KC=32, 256 thr, 8x4 per thread) ----

// Vs GEMM: Vs([H][BN][K] contiguous) <- cur(20000x128) @ Wcat(128x128)
__global__ __launch_bounds__(256) void k_gemm_vs(const float* __restrict__ A,
                                                 const float* __restrict__ Bw,
                                                 float* __restrict__ Vs) {
    __shared__ float At[32][68];
    __shared__ float Bs[32][128];
    const int tid = threadIdx.x;
    const int row0 = blockIdx.x * 64;
    const int tx = tid & 31, ty = tid >> 5;
    float acc[8][4] = {};
    for (int kc = 0; kc < 128; kc += 32) {
#pragma unroll
        for (int it = 0; it < 2; ++it) {
            int idx = tid + it * 256;
            int r = idx >> 3, k4 = (idx & 7) << 2;
            int gr = row0 + r;
            float4 v = make_float4(0.f, 0.f, 0.f, 0.f);
            if (gr < BN_) v = *(const float4*)(A + gr * D_ + kc + k4);
            At[k4 + 0][r] = v.x; At[k4 + 1][r] = v.y;
            At[k4 + 2][r] = v.z; At[k4 + 3][r] = v.w;
        }
#pragma unroll
        for (int it = 0; it < 4; ++it) {
            int idx = tid + it * 256;
            int kk = idx >> 5, c4 = (idx & 31) << 2;
            *(float4*)&Bs[kk][c4] = *(const float4*)(Bw + (kc + kk) * 128 + c4);
        }
        __syncthreads();
#pragma unroll
        for (int kk = 0; kk < 32; ++kk) {
            float4 b  = *(const float4*)&Bs[kk][tx << 2];
            float4 a0 = *(const float4*)&At[kk][ty << 3];
            float4 a1 = *(const float4*)&At[kk][(ty << 3) + 4];
            float ar[8] = {a0.x, a0.y, a0.z, a0.w, a1.x, a1.y, a1.z, a1.w};
            float br[4] = {b.x, b.y, b.z, b.w};
#pragma unroll
            for (int i = 0; i < 8; ++i)
#pragma unroll
                for (int j = 0; j < 4; ++j)
                    acc[i][j] = fmaf(ar[i], br[j], acc[i][j]);
        }
        __syncthreads();
    }
    const int c = tx << 2;
    const int h = c >> 4, k = c & 15;
#pragma unroll
    for (int i = 0; i < 8; ++i) {
        int gr = row0 + (ty << 3) + i;
        if (gr < BN_) {
            float4 o = make_float4(acc[i][0], acc[i][1], acc[i][2], acc[i][3]);
            *(float4*)(Vs + h * (BN_ * 16) + gr * 16 + k) = o;
        }
    }
}

// out GEMM + residual: h1 = cur + flag * (Vs(20000x128 view) @ Wout_l(128x128))
__global__ __launch_bounds__(256) void k_gemm_out(const float* __restrict__ A,
                                                  const float* __restrict__ Bw,
                                                  const float* __restrict__ cur,
                                                  const float* __restrict__ flag,
                                                  float* __restrict__ Cout) {
    __shared__ float At[32][68];
    __shared__ float Bs[32][128];
    const int tid = threadIdx.x;
    const int row0 = blockIdx.x * 64;
    const int tx = tid & 31, ty = tid >> 5;
    float acc[8][4] = {};
    for (int kc = 0; kc < 128; kc += 32) {
#pragma unroll
        for (int it = 0; it < 2; ++it) {
            int idx = tid + it * 256;
            int r = idx >> 3, k4 = (idx & 7) << 2;
            int gr = row0 + r;
            float4 v = make_float4(0.f, 0.f, 0.f, 0.f);
            if (gr < BN_) v = *(const float4*)(A + gr * D_ + kc + k4);
            At[k4 + 0][r] = v.x; At[k4 + 1][r] = v.y;
            At[k4 + 2][r] = v.z; At[k4 + 3][r] = v.w;
        }
#pragma unroll
        for (int it = 0; it < 4; ++it) {
            int idx = tid + it * 256;
            int kk = idx >> 5, c4 = (idx & 31) << 2;
            *(float4*)&Bs[kk][c4] = *(const float4*)(Bw + (kc + kk) * 128 + c4);
        }
        __syncthreads();
#pragma unroll
        for (int kk = 0; kk < 32; ++kk) {
            float4 b  = *(const float4*)&Bs[kk][tx << 2];
            float4 a0 = *(const float4*)&At[kk][ty << 3];
            float4 a1 = *(const float4*)&At[kk][(ty << 3) + 4];
            float ar[8] = {a0.x, a0.y, a0.z, a0.w, a1.x, a1.y, a1.z, a1.w};
            float br[4] = {b.x, b.y, b.z, b.w};
#pragma unroll
            for (int i = 0; i < 8; ++i)
#pragma unroll
                for (int j = 0; j < 4; ++j)
                    acc[i][j] = fmaf(ar[i], br[j], acc[i][j]);
        }
        __syncthreads();
    }
    const int c = tx << 2;
#pragma unroll
    for (int i = 0; i < 8; ++i) {
        int gr = row0 + (ty << 3) + i;
        if (gr < BN_) {
            float f = flag[gr];
            float4 cv = *(const float4*)(cur + gr * D_ + c);
            float4 o;
            o.x = cv.x + f * acc[i][0];
            o.y = cv.y + f * acc[i][1];
            o.z = cv.z + f * acc[i][2];
            o.w = cv.w + f * acc[i][3];
            *(float4*)(Cout + gr * D_ + c) = o;
        }
    }
}

// FF1: T[:, cb..cb+127] = relu( bn1(h1) @ W1[:, cb..] + b1 )   (grid 313 x 4)
__global__ __launch_bounds__(256) void k_gemm_ff1(const float* __restrict__ H1,
                                                  const float* __restrict__ W1f,
                                                  const float* __restrict__ ss,
                                                  const float* __restrict__ b1,
                                                  float* __restrict__ T) {
    __shared__ float At[32][68];
    __shared__ float Bs[32][128];
    const int tid = threadIdx.x;
    const int row0 = blockIdx.x * 64;
    const int cb = blockIdx.y * 128;
    const int tx = tid & 31, ty = tid >> 5;
    float acc[8][4] = {};
    for (int kc = 0; kc < 128; kc += 32) {
#pragma unroll
        for (int it = 0; it < 2; ++it) {
            int idx = tid + it * 256;
            int r = idx >> 3, k4 = (idx & 7) << 2;
            int gr = row0 + r;
            float4 v = make_float4(0.f, 0.f, 0.f, 0.f);
            if (gr < BN_) v = *(const float4*)(H1 + gr * D_ + kc + k4);
            int kd = kc + k4;
            v.x = v.x * ss[kd + 0] + ss[128 + kd + 0];
            v.y = v.y * ss[kd + 1] + ss[128 + kd + 1];
            v.z = v.z * ss[kd + 2] + ss[128 + kd + 2];
            v.w = v.w * ss[kd + 3] + ss[128 + kd + 3];
            At[k4 + 0][r] = v.x; At[k4 + 1][r] = v.y;
            At[k4 + 2][r] = v.z; At[k4 + 3][r] = v.w;
        }
#pragma unroll
        for (int it = 0; it < 4; ++it) {
            int idx = tid + it * 256;
            int kk = idx >> 5, c4 = (idx & 31) << 2;
            *(float4*)&Bs[kk][c4] = *(const float4*)(W1f + (kc + kk) * FF_ + cb + c4);
        }
        __syncthreads();
#pragma unroll
        for (int kk = 0; kk < 32; ++kk) {
            float4 b  = *(const float4*)&Bs[kk][tx << 2];
            float4 a0 = *(const float4*)&At[kk][ty << 3];
            float4 a1 = *(const float4*)&At[kk][(ty << 3) + 4];
            float ar[8] = {a0.x, a0.y, a0.z, a0.w, a1.x, a1.y, a1.z, a1.w};
            float br[4] = {b.x, b.y, b.z, b.w};
#pragma unroll
            for (int i = 0; i < 8; ++i)
#pragma unroll
                for (int j = 0; j < 4; ++j)
                    acc[i][j] = fmaf(ar[i], br[j], acc[i][j]);
        }
        __syncthreads();
    }
    const int c = tx << 2;
    float bb[4];
#pragma unroll
    for (int j = 0; j < 4; ++j) bb[j] = b1[cb + c + j];
#pragma unroll
    for (int i = 0; i < 8; ++i) {
        int gr = row0 + (ty << 3) + i;
        if (gr < BN_) {
            float4 o;
            o.x = fmaxf(acc[i][0] + bb[0], 0.f);
            o.y = fmaxf(acc[i][1] + bb[1], 0.f);
            o.z = fmaxf(acc[i][2] + bb[2], 0.f);
            o.w = fmaxf(acc[i][3] + bb[3], 0.f);
            *(float4*)(T + gr * FF_ + cb + c) = o;
        }
    }
}

// FF2 + residual: h2 = bn1(h1) + T @ W2 + b2
__global__ __launch_bounds__(256) void k_gemm_ff2(const float* __restrict__ T,
                                                  const float* __restrict__ W2f,
                                                  const float* __restrict__ H1,
                                                  const float* __restrict__ ss,
                                                  const float* __restrict__ b2,
                                                  float* __restrict__ H2) {
    __shared__ float At[32][68];
    __shared__ float Bs[32][128];
    const int tid = threadIdx.x;
    const int row0 = blockIdx.x * 64;
    const int tx = tid & 31, ty = tid >> 5;
    float acc[8][4] = {};
    for (int kc = 0; kc < FF_; kc += 32) {
#pragma unroll
        for (int it = 0; it < 2; ++it) {
            int idx = tid + it * 256;
            int r = idx >> 3, k4 = (idx & 7) << 2;
            int gr = row0 + r;
            float4 v = make_float4(0.f, 0.f, 0.f, 0.f);
            if (gr < BN_) v = *(const float4*)(T + gr * FF_ + kc + k4);
            At[k4 + 0][r] = v.x; At[k4 + 1][r] = v.y;
            At[k4 + 2][r] = v.z; At[k4 + 3][r] = v.w;
        }
#pragma unroll
        for (int it = 0; it < 4; ++it) {
            int idx = tid + it * 256;
            int kk = idx >> 5, c4 = (idx & 31) << 2;
            *(float4*)&Bs[kk][c4] = *(const float4*)(W2f + (kc + kk) * D_ + c4);
        }
        __syncthreads();
#pragma unroll
        for (int kk = 0; kk < 32; ++kk) {
            float4 b  = *(const float4*)&Bs[kk][tx << 2];
            float4 a0 = *(const float4*)&At[kk][ty << 3];
            float4 a1 = *(const float4*)&At[kk][(ty << 3) + 4];
            float ar[8] = {a0.x, a0.y, a0.z, a0.w, a1.x, a1.y, a1.z, a1.w};
            float br[4] = {b.x, b.y, b.z, b.w};
#pragma unroll
            for (int i = 0; i < 8; ++i)
#pragma unroll
                for (int j = 0; j < 4; ++j)
                    acc[i][j] = fmaf(ar[i], br[j], acc[i][j]);
        }
        __syncthreads();
    }
    const int c = tx << 2;
    float sc[4], sh[4], bb[4];
#pragma unroll
    for (int j = 0; j < 4; ++j) {
        sc[j] = ss[c + j];
        sh[j] = ss[128 + c + j];
        bb[j] = b2[c + j];
    }
#pragma unroll
    for (int i = 0; i < 8; ++i) {
        int gr = row0 + (ty << 3) + i;
        if (gr < BN_) {
            float4 hv = *(const float4*)(H1 + gr * D_ + c);
            float4 o;
            o.x = hv.x * sc[0] + sh[0] + acc[i][0] + bb[0];
            o.y = hv.y * sc[1] + sh[1] + acc[i][1] + bb[1];
            o.z = hv.z * sc[2] + sh[2] + acc[i][2] + bb[2];
            o.w = hv.w * sc[3] + sh[3] + acc[i][3] + bb[3];
            *(float4*)(H2 + gr * D_ + c) = o;
        }
    }
}

// apply BN: out = h2*scale + shift
__global__ __launch_bounds__(256) void k_apply(const float* __restrict__ H2,
                                               const float* __restrict__ ss,
                                               float* __restrict__ outF) {
    int i = blockIdx.x * 256 + threadIdx.x;
    if (i >= BN_ * D_) return;
    int c = i & 127;
    outF[i] = H2[i] * ss[c] + ss[128 + c];
}

// ---------------- launch ----------------

extern "C" void kernel_launch(void* const* d_in, const int* in_sizes, int n_in,
                              void* d_out, int out_size, void* d_ws, size_t ws_size,
                              hipStream_t stream) {
    (void)in_sizes; (void)n_in; (void)out_size; (void)ws_size;
    const float* x    = (const float*)d_in[0];
    const int*   edge = (const int*)d_in[1];
    const float* Wv   = (const float*)d_in[4];
    const float* Wout = (const float*)d_in[5];
    const float* bn1w = (const float*)d_in[6];
    const float* bn1b = (const float*)d_in[7];
    const float* W1   = (const float*)d_in[8];
    const float* b1   = (const float*)d_in[9];
    const float* W2   = (const float*)d_in[10];
    const float* b2   = (const float*)d_in[11];
    const float* bn2w = (const float*)d_in[12];
    const float* bn2b = (const float*)d_in[13];

    float* ws    = (float*)d_ws;
    float* bufA  = ws;                  // 2,560,000
    float* bufB  = ws + 2560000;        // 2,560,000
    float* Vs    = ws + 5120000;        // 2,560,000
    float* T     = ws + 7680000;        // 10,240,000
    float* flag  = ws + 17920000;       // 20,000
    float* part  = ws + 17940000;       // 51,200
    float* ss    = ws + 17991200;       // 512
    float* WcatF = ws + 17991712;       // 49,152
    // total ~18.04M floats = ~72.2 MiB

    k_copy4<<<2500, 256, 0, stream>>>((const float4*)x, (float4*)bufA, 640000);
    k_wcat<<<192, 256, 0, stream>>>(Wv, WcatF);
    k_zero<<<79, 256, 0, stream>>>(flag, BN_);
    k_flag<<<1250, 256, 0, stream>>>(edge + E_, flag);

    float* cur = bufA;
    float* oth = bufB;
    for (int l = 0; l < 3; ++l) {
        k_gemm_vs<<<NBLK, 256, 0, stream>>>(cur, WcatF + l * 16384, Vs);
        k_gemm_out<<<NBLK, 256, 0, stream>>>(Vs, Wout + l * 16384, cur, flag, oth);
        k_stats<<<200, 256, 0, stream>>>(oth, part);
        k_bnfin<<<1, 128, 0, stream>>>(part, bn1w + l * 128, bn1b + l * 128, ss);
        k_gemm_ff1<<<dim3(NBLK, 4), 256, 0, stream>>>(oth, W1 + l * 65536, ss,
                                                      b1 + l * 512, T);
        k_gemm_ff2<<<NBLK, 256, 0, stream>>>(T, W2 + l * 65536, oth, ss,
                                             b2 + l * 128, cur);
        k_stats<<<200, 256, 0, stream>>>(cur, part);
        k_bnfin<<<1, 128, 0, stream>>>(part, bn2w + l * 128, bn2b + l * 128, ss + 256);
        if (l < 2) {
            k_apply<<<10000, 256, 0, stream>>>(cur, ss + 256, oth);
            float* tmp = cur; cur = oth; oth = tmp;
        } else {
            k_apply<<<10000, 256, 0, stream>>>(cur, ss + 256, (float*)d_out);
        }
    }
}

// Round 4
// 624.840 us; speedup vs baseline: 1.0440x; 1.0440x over previous
//
#include <hip/hip_runtime.h>
#include <hip/hip_bf16.h>

#define BN_ 20000
#define D_ 128
#define FF_ 512
#define E_ 320000
#define NBLK 313   // ceil(20000/64)

// ---------------- small utility kernels ----------------

// Wcat[l][d][h*16+k] = Wv[l][h][d][k]
__global__ __launch_bounds__(256) void k_wcat(const float* __restrict__ Wv,
                                              float* __restrict__ Wcat) {
    int idx = blockIdx.x * 256 + threadIdx.x;
    if (idx >= 3 * 128 * 128) return;
    int l = idx / 16384, r = idx % 16384;
    int d = r >> 7, c = r & 127, h = c >> 4, k = c & 15;
    Wcat[idx] = Wv[((l * 8 + h) * 128 + d) * 16 + k];
}

__global__ __launch_bounds__(256) void k_init_ss(float* __restrict__ ss_id,
                                                 float* __restrict__ flag) {
    int i = blockIdx.x * 256 + threadIdx.x;
    if (blockIdx.x == 0) {
        if (threadIdx.x < 128) ss_id[threadIdx.x] = 1.0f;
        else ss_id[threadIdx.x] = 0.0f;
    }
    if (i < BN_) flag[i] = 0.0f;
}

__global__ __launch_bounds__(256) void k_flag(const int* __restrict__ dst,
                                              float* __restrict__ flag) {
    int e = blockIdx.x * 256 + threadIdx.x;
    if (e < E_) flag[dst[e]] = 1.0f;
}

// bnfin: reduce part(313x128 sums + 313x128 sumsq) -> ss{scale,shift}
__global__ __launch_bounds__(128) void k_bnfin(const float* __restrict__ part,
                                               const float* __restrict__ w,
                                               const float* __restrict__ bb,
                                               float* __restrict__ ss) {
    int c = threadIdx.x;
    float s = 0.f, q = 0.f;
    for (int i = 0; i < NBLK; ++i) {
        s += part[i * 128 + c];
        q += part[NBLK * 128 + i * 128 + c];
    }
    float mu  = s * (1.f / 20000.f);
    float var = q * (1.f / 20000.f) - mu * mu;
    var = fmaxf(var, 0.f);
    float rstd  = rsqrtf(var + 1e-5f);
    float scale = w[c] * rstd;
    ss[c]       = scale;
    ss[128 + c] = bb[c] - mu * scale;
}

// ---------------- GAT GEMM 1 ----------------
// Vs([H][BN][K] memory order) = z @ Wcat_l,  z = cur*sc+sh (prev BN on the fly)
// grid (313, 2)
__global__ __launch_bounds__(256) void k_vs(const float* __restrict__ cur,
                                            const float* __restrict__ Wcl,
                                            const float* __restrict__ ssp,
                                            float* __restrict__ Vs) {
    __shared__ float At[32][68];
    __shared__ float Bs[32][68];
    const int tid = threadIdx.x;
    const int tx = tid & 15, ty = tid >> 4;
    const int row0 = blockIdx.x * 64, col0 = blockIdx.y * 64;
    float acc[4][4] = {};
    for (int kc = 0; kc < 128; kc += 32) {
#pragma unroll
        for (int it = 0; it < 2; ++it) {
            int idx = tid + it * 256;
            int r = idx >> 3, k4 = (idx & 7) << 2;
            int gr = row0 + r, kd = kc + k4;
            float4 v = make_float4(0.f, 0.f, 0.f, 0.f);
            if (gr < BN_) v = *(const float4*)(cur + gr * D_ + kd);
            v.x = v.x * ssp[kd + 0] + ssp[128 + kd + 0];
            v.y = v.y * ssp[kd + 1] + ssp[128 + kd + 1];
            v.z = v.z * ssp[kd + 2] + ssp[128 + kd + 2];
            v.w = v.w * ssp[kd + 3] + ssp[128 + kd + 3];
            At[k4 + 0][r] = v.x; At[k4 + 1][r] = v.y;
            At[k4 + 2][r] = v.z; At[k4 + 3][r] = v.w;
        }
#pragma unroll
        for (int it = 0; it < 2; ++it) {
            int idx = tid + it * 256;
            int kk = idx >> 4, c4 = (idx & 15) << 2;
            *(float4*)&Bs[kk][c4] = *(const float4*)(Wcl + (kc + kk) * 128 + col0 + c4);
        }
        __syncthreads();
#pragma unroll
        for (int kk = 0; kk < 32; ++kk) {
            float4 a = *(const float4*)&At[kk][ty << 2];
            float4 b = *(const float4*)&Bs[kk][tx << 2];
            float ar[4] = {a.x, a.y, a.z, a.w};
            float br[4] = {b.x, b.y, b.z, b.w};
#pragma unroll
            for (int i = 0; i < 4; ++i)
#pragma unroll
                for (int j = 0; j < 4; ++j)
                    acc[i][j] = fmaf(ar[i], br[j], acc[i][j]);
        }
        __syncthreads();
    }
    // store into [H][BN][K] layout: col c -> head h = c/16, k = c%16
    const int c = col0 + (tx << 2);
    const int h = c >> 4, k = c & 15;
#pragma unroll
    for (int i = 0; i < 4; ++i) {
        int gr = row0 + (ty << 2) + i;
        if (gr < BN_) {
            float4 o = make_float4(acc[i][0], acc[i][1], acc[i][2], acc[i][3]);
            *(float4*)(Vs + h * (BN_ * 16) + gr * 16 + k) = o;
        }
    }
}

// ---------------- GAT GEMM 2 ----------------
// H1 = z + flag .* (Vs_flatview(20000x128) @ Wout_l),  z = cur*sc+sh
// also emits per-block column partial sums/sumsq of H1. grid (313, 2)
__global__ __launch_bounds__(256) void k_out(const float* __restrict__ Vs,
                                             const float* __restrict__ Wol,
                                             const float* __restrict__ cur,
                                             const float* __restrict__ ssp,
                                             const float* __restrict__ flag,
                                             float* __restrict__ H1,
                                             float* __restrict__ part) {
    __shared__ float At[32][68];
    __shared__ float Bs[32][68];
    const int tid = threadIdx.x;
    const int tx = tid & 15, ty = tid >> 4;
    const int row0 = blockIdx.x * 64, col0 = blockIdx.y * 64;
    float acc[4][4] = {};
    for (int kc = 0; kc < 128; kc += 32) {
#pragma unroll
        for (int it = 0; it < 2; ++it) {
            int idx = tid + it * 256;
            int r = idx >> 3, k4 = (idx & 7) << 2;
            int gr = row0 + r;
            float4 v = make_float4(0.f, 0.f, 0.f, 0.f);
            if (gr < BN_) v = *(const float4*)(Vs + gr * D_ + kc + k4);
            At[k4 + 0][r] = v.x; At[k4 + 1][r] = v.y;
            At[k4 + 2][r] = v.z; At[k4 + 3][r] = v.w;
        }
#pragma unroll
        for (int it = 0; it < 2; ++it) {
            int idx = tid + it * 256;
            int kk = idx >> 4, c4 = (idx & 15) << 2;
            *(float4*)&Bs[kk][c4] = *(const float4*)(Wol + (kc + kk) * 128 + col0 + c4);
        }
        __syncthreads();
#pragma unroll
        for (int kk = 0; kk < 32; ++kk) {
            float4 a = *(const float4*)&At[kk][ty << 2];
            float4 b = *(const float4*)&Bs[kk][tx << 2];
            float ar[4] = {a.x, a.y, a.z, a.w};
            float br[4] = {b.x, b.y, b.z, b.w};
#pragma unroll
            for (int i = 0; i < 4; ++i)
#pragma unroll
                for (int j = 0; j < 4; ++j)
                    acc[i][j] = fmaf(ar[i], br[j], acc[i][j]);
        }
        __syncthreads();
    }
    const int c = col0 + (tx << 2);
    float sc[4], sh[4];
#pragma unroll
    for (int j = 0; j < 4; ++j) { sc[j] = ssp[c + j]; sh[j] = ssp[128 + c + j]; }
    float cs[4] = {}, cq[4] = {};
#pragma unroll
    for (int i = 0; i < 4; ++i) {
        int gr = row0 + (ty << 2) + i;
        if (gr < BN_) {
            float f = flag[gr];
            float4 cv = *(const float4*)(cur + gr * D_ + c);
            float4 o;
            o.x = cv.x * sc[0] + sh[0] + f * acc[i][0];
            o.y = cv.y * sc[1] + sh[1] + f * acc[i][1];
            o.z = cv.z * sc[2] + sh[2] + f * acc[i][2];
            o.w = cv.w * sc[3] + sh[3] + f * acc[i][3];
            *(float4*)(H1 + gr * D_ + c) = o;
            cs[0] += o.x; cq[0] += o.x * o.x;
            cs[1] += o.y; cq[1] += o.y * o.y;
            cs[2] += o.z; cq[2] += o.z * o.z;
            cs[3] += o.w; cq[3] += o.w * o.w;
        }
    }
    float* redS = &At[0][0];
    float* redQ = &Bs[0][0];
#pragma unroll
    for (int j = 0; j < 4; ++j) {
        redS[ty * 64 + (tx << 2) + j] = cs[j];
        redQ[ty * 64 + (tx << 2) + j] = cq[j];
    }
    __syncthreads();
    if (tid < 64) {
        float s = 0.f, q = 0.f;
#pragma unroll
        for (int t = 0; t < 16; ++t) { s += redS[t * 64 + tid]; q += redQ[t * 64 + tid]; }
        part[blockIdx.x * 128 + col0 + tid] = s;
        part[NBLK * 128 + blockIdx.x * 128 + col0 + tid] = q;
    }
}

// ---------------- FF1 ----------------
// T = relu( (H1*sc+sh) @ W1_l + b1_l ), grid (313,8)
__global__ __launch_bounds__(256) void k_ff1(const float* __restrict__ H1,
                                             const float* __restrict__ W1l,
                                             const float* __restrict__ ss,
                                             const float* __restrict__ b1l,
                                             float* __restrict__ T) {
    __shared__ float At[32][68];
    __shared__ float Bs[32][68];
    const int tid = threadIdx.x;
    const int tx = tid & 15, ty = tid >> 4;
    const int row0 = blockIdx.x * 64, col0 = blockIdx.y * 64;
    float acc[4][4] = {};
    for (int kc = 0; kc < 128; kc += 32) {
#pragma unroll
        for (int it = 0; it < 2; ++it) {
            int idx = tid + it * 256;
            int r = idx >> 3, k4 = (idx & 7) << 2;
            int gr = row0 + r, kd = kc + k4;
            float4 v = make_float4(0.f, 0.f, 0.f, 0.f);
            if (gr < BN_) v = *(const float4*)(H1 + gr * D_ + kd);
            v.x = v.x * ss[kd + 0] + ss[128 + kd + 0];
            v.y = v.y * ss[kd + 1] + ss[128 + kd + 1];
            v.z = v.z * ss[kd + 2] + ss[128 + kd + 2];
            v.w = v.w * ss[kd + 3] + ss[128 + kd + 3];
            At[k4 + 0][r] = v.x; At[k4 + 1][r] = v.y;
            At[k4 + 2][r] = v.z; At[k4 + 3][r] = v.w;
        }
#pragma unroll
        for (int it = 0; it < 2; ++it) {
            int idx = tid + it * 256;
            int kk = idx >> 4, c4 = (idx & 15) << 2;
            *(float4*)&Bs[kk][c4] = *(const float4*)(W1l + (kc + kk) * FF_ + col0 + c4);
        }
        __syncthreads();
#pragma unroll
        for (int kk = 0; kk < 32; ++kk) {
            float4 a = *(const float4*)&At[kk][ty << 2];
            float4 b = *(const float4*)&Bs[kk][tx << 2];
            float ar[4] = {a.x, a.y, a.z, a.w};
            float br[4] = {b.x, b.y, b.z, b.w};
#pragma unroll
            for (int i = 0; i < 4; ++i)
#pragma unroll
                for (int j = 0; j < 4; ++j)
                    acc[i][j] = fmaf(ar[i], br[j], acc[i][j]);
        }
        __syncthreads();
    }
    const int c = col0 + (tx << 2);
    float bb[4];
#pragma unroll
    for (int j = 0; j < 4; ++j) bb[j] = b1l[c + j];
#pragma unroll
    for (int i = 0; i < 4; ++i) {
        int gr = row0 + (ty << 2) + i;
        if (gr < BN_) {
            float4 o;
            o.x = fmaxf(acc[i][0] + bb[0], 0.f);
            o.y = fmaxf(acc[i][1] + bb[1], 0.f);
            o.z = fmaxf(acc[i][2] + bb[2], 0.f);
            o.w = fmaxf(acc[i][3] + bb[3], 0.f);
            *(float4*)(T + gr * FF_ + c) = o;
        }
    }
}

// ---------------- FF2 ----------------
// H2 = (H1*sc+sh) + T @ W2_l + b2_l ; emits col stats of H2. grid (313,2)
__global__ __launch_bounds__(256) void k_ff2(const float* __restrict__ T,
                                             const float* __restrict__ W2l,
                                             const float* __restrict__ H1,
                                             const float* __restrict__ ss,
                                             const float* __restrict__ b2l,
                                             float* __restrict__ H2,
                                             float* __restrict__ part) {
    __shared__ float At[32][68];
    __shared__ float Bs[32][68];
    const int tid = threadIdx.x;
    const int tx = tid & 15, ty = tid >> 4;
    const int row0 = blockIdx.x * 64, col0 = blockIdx.y * 64;
    float acc[4][4] = {};
    for (int kc = 0; kc < FF_; kc += 32) {
#pragma unroll
        for (int it = 0; it < 2; ++it) {
            int idx = tid + it * 256;
            int r = idx >> 3, k4 = (idx & 7) << 2;
            int gr = row0 + r;
            float4 v = make_float4(0.f, 0.f, 0.f, 0.f);
            if (gr < BN_) v = *(const float4*)(T + gr * FF_ + kc + k4);
            At[k4 + 0][r] = v.x; At[k4 + 1][r] = v.y;
            At[k4 + 2][r] = v.z; At[k4 + 3][r] = v.w;
        }
#pragma unroll
        for (int it = 0; it < 2; ++it) {
            int idx = tid + it * 256;
            int kk = idx >> 4, c4 = (idx & 15) << 2;
            *(float4*)&Bs[kk][c4] = *(const float4*)(W2l + (kc + kk) * D_ + col0 + c4);
        }
        __syncthreads();
#pragma unroll
        for (int kk = 0; kk < 32; ++kk) {
            float4 a = *(const float4*)&At[kk][ty << 2];
            float4 b = *(const float4*)&Bs[kk][tx << 2];
            float ar[4] = {a.x, a.y, a.z, a.w};
            float br[4] = {b.x, b.y, b.z, b.w};
#pragma unroll
            for (int i = 0; i < 4; ++i)
#pragma unroll
                for (int j = 0; j < 4; ++j)
                    acc[i][j] = fmaf(ar[i], br[j], acc[i][j]);
        }
        __syncthreads();
    }
    const int c = col0 + (tx << 2);
    float sc[4], sh[4], bb[4];
#pragma unroll
    for (int j = 0; j < 4; ++j) {
        sc[j] = ss[c + j]; sh[j] = ss[128 + c + j]; bb[j] = b2l[c + j];
    }
    float cs[4] = {}, cq[4] = {};
#pragma unroll
    for (int i = 0; i < 4; ++i) {
        int gr = row0 + (ty << 2) + i;
        if (gr < BN_) {
            float4 hv = *(const float4*)(H1 + gr * D_ + c);
            float4 o;
            o.x = hv.x * sc[0] + sh[0] + acc[i][0] + bb[0];
            o.y = hv.y * sc[1] + sh[1] + acc[i][1] + bb[1];
            o.z = hv.z * sc[2] + sh[2] + acc[i][2] + bb[2];
            o.w = hv.w * sc[3] + sh[3] + acc[i][3] + bb[3];
            *(float4*)(H2 + gr * D_ + c) = o;
            cs[0] += o.x; cq[0] += o.x * o.x;
            cs[1] += o.y; cq[1] += o.y * o.y;
            cs[2] += o.z; cq[2] += o.z * o.z;
            cs[3] += o.w; cq[3] += o.w * o.w;
        }
    }
    float* redS = &At[0][0];
    float* redQ = &Bs[0][0];
#pragma unroll
    for (int j = 0; j < 4; ++j) {
        redS[ty * 64 + (tx << 2) + j] = cs[j];
        redQ[ty * 64 + (tx << 2) + j] = cq[j];
    }
    __syncthreads();
    if (tid < 64) {
        float s = 0.f, q = 0.f;
#pragma unroll
        for (int t = 0; t < 16; ++t) { s += redS[t * 64 + tid]; q += redQ[t * 64 + tid]; }
        part[blockIdx.x * 128 + col0 + tid] = s;
        part[NBLK * 128 + blockIdx.x * 128 + col0 + tid] = q;
    }
}

// final: out = H2*scale + shift (float4)
__global__ __launch_bounds__(256) void k_apply(const float4* __restrict__ H2,
                                               const float* __restrict__ ss,
                                               float4* __restrict__ out) {
    int i = blockIdx.x * 256 + threadIdx.x;
    if (i >= BN_ * D_ / 4) return;
    int c = (i & 31) << 2;
    float4 v = H2[i];
    v.x = v.x * ss[c + 0] + ss[128 + c + 0];
    v.y = v.y * ss[c + 1] + ss[128 + c + 1];
    v.z = v.z * ss[c + 2] + ss[128 + c + 2];
    v.w = v.w * ss[c + 3] + ss[128 + c + 3];
    out[i] = v;
}

// ---------------- launch ----------------

extern "C" void kernel_launch(void* const* d_in, const int* in_sizes, int n_in,
                              void* d_out, int out_size, void* d_ws, size_t ws_size,
                              hipStream_t stream) {
    (void)in_sizes; (void)n_in; (void)out_size; (void)ws_size;
    const float* x    = (const float*)d_in[0];
    const int*   edge = (const int*)d_in[1];
    const float* Wv   = (const float*)d_in[4];
    const float* Wout = (const float*)d_in[5];
    const float* bn1w = (const float*)d_in[6];
    const float* bn1b = (const float*)d_in[7];
    const float* W1   = (const float*)d_in[8];
    const float* b1   = (const float*)d_in[9];
    const float* W2   = (const float*)d_in[10];
    const float* b2   = (const float*)d_in[11];
    const float* bn2w = (const float*)d_in[12];
    const float* bn2b = (const float*)d_in[13];

    float* ws    = (float*)d_ws;
    float* bufA  = ws;                    // 2,560,000  (H2)
    float* bufB  = ws + 2560000;          // 2,560,000  (H1)
    float* Vs    = ws + 5120000;          // 2,560,000
    float* T     = ws + 7680000;          // 10,240,000
    float* flag  = ws + 17920000;         // 20,000
    float* part  = ws + 17940000;         // 80,128
    float* ss_id = ws + 18020200;         // 256
    float* ssA   = ws + 18020456;         // 256  (bn1 scale/shift)
    float* ssB   = ws + 18020712;         // 256  (bn2 scale/shift)
    float* Wcat  = ws + 18021000;         // 49,152
    // total ~18.07M floats = ~72.3 MiB

    k_wcat<<<192, 256, 0, stream>>>(Wv, Wcat);
    k_init_ss<<<79, 256, 0, stream>>>(ss_id, flag);
    k_flag<<<1250, 256, 0, stream>>>(edge + E_, flag);

    for (int l = 0; l < 3; ++l) {
        const float* cur = (l == 0) ? x : bufA;
        const float* ssp = (l == 0) ? ss_id : ssB;
        k_vs<<<dim3(NBLK, 2), 256, 0, stream>>>(cur, Wcat + l * 16384, ssp, Vs);
        k_out<<<dim3(NBLK, 2), 256, 0, stream>>>(Vs, Wout + l * 16384, cur, ssp,
                                                 flag, bufB, part);
        k_bnfin<<<1, 128, 0, stream>>>(part, bn1w + l * 128, bn1b + l * 128, ssA);
        k_ff1<<<dim3(NBLK, 8), 256, 0, stream>>>(bufB, W1 + l * 65536, ssA,
                                                 b1 + l * 512, T);
        k_ff2<<<dim3(NBLK, 2), 256, 0, stream>>>(T, W2 + l * 65536, bufB, ssA,
                                                 b2 + l * 128, bufA, part);
        k_bnfin<<<1, 128, 0, stream>>>(part, bn2w + l * 128, bn2b + l * 128, ssB);
    }
    k_apply<<<2500, 256, 0, stream>>>((const float4*)bufA, ssB, (float4*)d_out);
}

// Round 5
// 437.583 us; speedup vs baseline: 1.4908x; 1.4279x over previous
//
#include <hip/hip_runtime.h>
#include <hip/hip_bf16.h>

#define BN_ 20000
#define D_ 128
#define FF_ 512
#define E_ 320000
#define NBLK 313   // ceil(20000/64)
#define LSTR 136   // LDS row stride in bf16 elems (128 + 8 pad; 272 B, 16B-aligned)

typedef __attribute__((ext_vector_type(8))) short bf16x8;
typedef __attribute__((ext_vector_type(4))) float f32x4;

__device__ __forceinline__ unsigned short f2b(float f) {
    unsigned int u = __float_as_uint(f);
    u = (u + 0x7FFFu + ((u >> 16) & 1u)) >> 16;
    return (unsigned short)u;
}

// ---------------- prep kernels ----------------

// WcatT[l][n=h*16+kk][k=d] = Wv[l][h][d][kk]  (bf16)
__global__ __launch_bounds__(256) void k_wvt(const float* __restrict__ Wv,
                                             unsigned short* __restrict__ dst) {
    int idx = blockIdx.x * 256 + threadIdx.x;
    if (idx >= 3 * 16384) return;
    int l = idx / 16384, r = idx % 16384;
    int n = r >> 7, k = r & 127;
    int h = n >> 4, kk = n & 15;
    dst[idx] = f2b(Wv[((l * 8 + h) * 128 + k) * 16 + kk]);
}

// dst[l][n][k] = bf16(src[l][k][n])
__global__ __launch_bounds__(256) void k_tr(const float* __restrict__ src,
                                            unsigned short* __restrict__ dst,
                                            int K, int N, int total) {
    int idx = blockIdx.x * 256 + threadIdx.x;
    if (idx >= total) return;
    int kn = K * N;
    int l = idx / kn, r = idx % kn;
    int n = r / K, k = r % K;
    dst[idx] = f2b(src[l * kn + k * N + n]);
}

__global__ __launch_bounds__(256) void k_init_ss(float* __restrict__ ss_id,
                                                 float* __restrict__ flag) {
    int i = blockIdx.x * 256 + threadIdx.x;
    if (blockIdx.x == 0) {
        if (threadIdx.x < 128) ss_id[threadIdx.x] = 1.0f;
        else ss_id[threadIdx.x] = 0.0f;
    }
    if (i < BN_) flag[i] = 0.0f;
}

__global__ __launch_bounds__(256) void k_flag(const int* __restrict__ dst,
                                              float* __restrict__ flag) {
    int e = blockIdx.x * 256 + threadIdx.x;
    if (e < E_) flag[dst[e]] = 1.0f;
}

__global__ __launch_bounds__(128) void k_bnfin(const float* __restrict__ part,
                                               const float* __restrict__ w,
                                               const float* __restrict__ bb,
                                               float* __restrict__ ss) {
    int c = threadIdx.x;
    float s = 0.f, q = 0.f;
    for (int i = 0; i < NBLK; ++i) {
        s += part[i * 128 + c];
        q += part[NBLK * 128 + i * 128 + c];
    }
    float mu  = s * (1.f / 20000.f);
    float var = q * (1.f / 20000.f) - mu * mu;
    var = fmaxf(var, 0.f);
    float rstd  = rsqrtf(var + 1e-5f);
    float scale = w[c] * rstd;
    ss[c]       = scale;
    ss[128 + c] = bb[c] - mu * scale;
}

// ---------------- MFMA GEMM kernels ----------------
// Block: 256 thr = 4 waves (2x2), tile 64x64, K-chunk 128 staged in LDS.
// Wave (wm,wn) does 32x32 = 2x2 mfma_f32_16x16x32_bf16 subtiles.
// A[m=lane&15][k=quad*8+j]; B[k=quad*8+j][n=lane&15]; D col=lane&15,row=quad*4+reg.

// k_vs: Vs([H][BN][16] scrambled, bf16) = (H*sc+sh) @ WcatT_l^T ; grid (313,2)
__global__ __launch_bounds__(256) void k_vs(const float* __restrict__ H,
                                            const float* __restrict__ ssp,
                                            const unsigned short* __restrict__ Bt,
                                            unsigned short* __restrict__ Vs) {
    __shared__ unsigned short As[64 * LSTR];
    __shared__ unsigned short Bs[64 * LSTR];
    const int tid = threadIdx.x;
    const int row0 = blockIdx.x * 64, col0 = blockIdx.y * 64;
#pragma unroll
    for (int it = 0; it < 4; ++it) {
        int idx = tid + it * 256;
        int m = idx >> 4, k0 = (idx & 15) << 3;
        int gr = row0 + m;
        float v[8];
        if (gr < BN_) {
            f32x4 v0 = *(const f32x4*)(H + gr * D_ + k0);
            f32x4 v1 = *(const f32x4*)(H + gr * D_ + k0 + 4);
            v[0] = v0.x; v[1] = v0.y; v[2] = v0.z; v[3] = v0.w;
            v[4] = v1.x; v[5] = v1.y; v[6] = v1.z; v[7] = v1.w;
        } else {
#pragma unroll
            for (int j = 0; j < 8; ++j) v[j] = 0.f;
        }
        unsigned int p[4];
#pragma unroll
        for (int j = 0; j < 4; ++j) {
            unsigned short lo = f2b(v[2 * j] * ssp[k0 + 2 * j] + ssp[128 + k0 + 2 * j]);
            unsigned short hi = f2b(v[2 * j + 1] * ssp[k0 + 2 * j + 1] + ssp[128 + k0 + 2 * j + 1]);
            p[j] = (unsigned int)lo | ((unsigned int)hi << 16);
        }
        uint4 w = make_uint4(p[0], p[1], p[2], p[3]);
        *(uint4*)&As[m * LSTR + k0] = w;
    }
#pragma unroll
    for (int it = 0; it < 4; ++it) {
        int idx = tid + it * 256;
        int n = idx >> 4, k0 = (idx & 15) << 3;
        *(uint4*)&Bs[n * LSTR + k0] = *(const uint4*)(Bt + (col0 + n) * D_ + k0);
    }
    __syncthreads();
    const int lane = tid & 63, wave = tid >> 6;
    const int l16 = lane & 15, quad = lane >> 4;
    const int wm = (wave >> 1) * 32, wn = (wave & 1) * 32;
    f32x4 acc[2][2] = {};
#pragma unroll
    for (int kb = 0; kb < 128; kb += 32) {
        bf16x8 a0 = *(bf16x8*)&As[(wm + l16) * LSTR + kb + quad * 8];
        bf16x8 a1 = *(bf16x8*)&As[(wm + 16 + l16) * LSTR + kb + quad * 8];
        bf16x8 b0 = *(bf16x8*)&Bs[(wn + l16) * LSTR + kb + quad * 8];
        bf16x8 b1 = *(bf16x8*)&Bs[(wn + 16 + l16) * LSTR + kb + quad * 8];
        acc[0][0] = __builtin_amdgcn_mfma_f32_16x16x32_bf16(a0, b0, acc[0][0], 0, 0, 0);
        acc[0][1] = __builtin_amdgcn_mfma_f32_16x16x32_bf16(a0, b1, acc[0][1], 0, 0, 0);
        acc[1][0] = __builtin_amdgcn_mfma_f32_16x16x32_bf16(a1, b0, acc[1][0], 0, 0, 0);
        acc[1][1] = __builtin_amdgcn_mfma_f32_16x16x32_bf16(a1, b1, acc[1][1], 0, 0, 0);
    }
#pragma unroll
    for (int i = 0; i < 2; ++i)
#pragma unroll
        for (int j = 0; j < 2; ++j) {
            int gc = col0 + wn + j * 16 + l16;
            int h = gc >> 4, kk = gc & 15;
#pragma unroll
            for (int r = 0; r < 4; ++r) {
                int gr = row0 + wm + i * 16 + quad * 4 + r;
                if (gr < BN_) Vs[h * (BN_ * 16) + gr * 16 + kk] = f2b(acc[i][j][r]);
            }
        }
}

// k_out: H1 = z + flag.*(VsFlat @ WoutT_l^T), z = H*sc+sh ; + BN stats. grid (313,2)
__global__ __launch_bounds__(256) void k_out(const unsigned short* __restrict__ Vs,
                                             const unsigned short* __restrict__ Bt,
                                             const float* __restrict__ H,
                                             const float* __restrict__ ssp,
                                             const float* __restrict__ flag,
                                             float* __restrict__ H1,
                                             float* __restrict__ part) {
    __shared__ unsigned short As[64 * LSTR];
    __shared__ unsigned short Bs[64 * LSTR];
    const int tid = threadIdx.x;
    const int row0 = blockIdx.x * 64, col0 = blockIdx.y * 64;
#pragma unroll
    for (int it = 0; it < 4; ++it) {
        int idx = tid + it * 256;
        int m = idx >> 4, k0 = (idx & 15) << 3;
        int gr = row0 + m;
        uint4 w = make_uint4(0u, 0u, 0u, 0u);
        if (gr < BN_) w = *(const uint4*)(Vs + gr * D_ + k0);
        *(uint4*)&As[m * LSTR + k0] = w;
    }
#pragma unroll
    for (int it = 0; it < 4; ++it) {
        int idx = tid + it * 256;
        int n = idx >> 4, k0 = (idx & 15) << 3;
        *(uint4*)&Bs[n * LSTR + k0] = *(const uint4*)(Bt + (col0 + n) * D_ + k0);
    }
    __syncthreads();
    const int lane = tid & 63, wave = tid >> 6;
    const int l16 = lane & 15, quad = lane >> 4;
    const int wm = (wave >> 1) * 32, wn = (wave & 1) * 32;
    f32x4 acc[2][2] = {};
#pragma unroll
    for (int kb = 0; kb < 128; kb += 32) {
        bf16x8 a0 = *(bf16x8*)&As[(wm + l16) * LSTR + kb + quad * 8];
        bf16x8 a1 = *(bf16x8*)&As[(wm + 16 + l16) * LSTR + kb + quad * 8];
        bf16x8 b0 = *(bf16x8*)&Bs[(wn + l16) * LSTR + kb + quad * 8];
        bf16x8 b1 = *(bf16x8*)&Bs[(wn + 16 + l16) * LSTR + kb + quad * 8];
        acc[0][0] = __builtin_amdgcn_mfma_f32_16x16x32_bf16(a0, b0, acc[0][0], 0, 0, 0);
        acc[0][1] = __builtin_amdgcn_mfma_f32_16x16x32_bf16(a0, b1, acc[0][1], 0, 0, 0);
        acc[1][0] = __builtin_amdgcn_mfma_f32_16x16x32_bf16(a1, b0, acc[1][0], 0, 0, 0);
        acc[1][1] = __builtin_amdgcn_mfma_f32_16x16x32_bf16(a1, b1, acc[1][1], 0, 0, 0);
    }
    __syncthreads();   // LDS reuse for stats
    float* Sred = (float*)As;  // [64][8]
    float* Qred = (float*)Bs;
    const int slot = (wave >> 1) * 4 + quad;
#pragma unroll
    for (int j = 0; j < 2; ++j) {
        int gc = col0 + wn + j * 16 + l16;
        float sc = ssp[gc], sh = ssp[128 + gc];
        float cs = 0.f, cq = 0.f;
#pragma unroll
        for (int i = 0; i < 2; ++i)
#pragma unroll
            for (int r = 0; r < 4; ++r) {
                int gr = row0 + wm + i * 16 + quad * 4 + r;
                if (gr < BN_) {
                    float z = H[gr * D_ + gc] * sc + sh;
                    float o = z + flag[gr] * acc[i][j][r];
                    H1[gr * D_ + gc] = o;
                    cs += o; cq += o * o;
                }
            }
        Sred[(wn + j * 16 + l16) * 8 + slot] = cs;
        Qred[(wn + j * 16 + l16) * 8 + slot] = cq;
    }
    __syncthreads();
    if (tid < 64) {
        float s = 0.f, q = 0.f;
#pragma unroll
        for (int t = 0; t < 8; ++t) { s += Sred[tid * 8 + t]; q += Qred[tid * 8 + t]; }
        part[blockIdx.x * 128 + col0 + tid] = s;
        part[NBLK * 128 + blockIdx.x * 128 + col0 + tid] = q;
    }
}

// k_ff1: T(bf16) = relu((H1*sc+sh) @ W1T_l^T + b1) ; grid (313,8)
__global__ __launch_bounds__(256) void k_ff1(const float* __restrict__ H1,
                                             const float* __restrict__ ss,
                                             const unsigned short* __restrict__ Bt,
                                             const float* __restrict__ b1l,
                                             unsigned short* __restrict__ T) {
    __shared__ unsigned short As[64 * LSTR];
    __shared__ unsigned short Bs[64 * LSTR];
    const int tid = threadIdx.x;
    const int row0 = blockIdx.x * 64, col0 = blockIdx.y * 64;
#pragma unroll
    for (int it = 0; it < 4; ++it) {
        int idx = tid + it * 256;
        int m = idx >> 4, k0 = (idx & 15) << 3;
        int gr = row0 + m;
        float v[8];
        if (gr < BN_) {
            f32x4 v0 = *(const f32x4*)(H1 + gr * D_ + k0);
            f32x4 v1 = *(const f32x4*)(H1 + gr * D_ + k0 + 4);
            v[0] = v0.x; v[1] = v0.y; v[2] = v0.z; v[3] = v0.w;
            v[4] = v1.x; v[5] = v1.y; v[6] = v1.z; v[7] = v1.w;
        } else {
#pragma unroll
            for (int j = 0; j < 8; ++j) v[j] = 0.f;
        }
        unsigned int p[4];
#pragma unroll
        for (int j = 0; j < 4; ++j) {
            unsigned short lo = f2b(v[2 * j] * ss[k0 + 2 * j] + ss[128 + k0 + 2 * j]);
            unsigned short hi = f2b(v[2 * j + 1] * ss[k0 + 2 * j + 1] + ss[128 + k0 + 2 * j + 1]);
            p[j] = (unsigned int)lo | ((unsigned int)hi << 16);
        }
        *(uint4*)&As[m * LSTR + k0] = make_uint4(p[0], p[1], p[2], p[3]);
    }
#pragma unroll
    for (int it = 0; it < 4; ++it) {
        int idx = tid + it * 256;
        int n = idx >> 4, k0 = (idx & 15) << 3;
        *(uint4*)&Bs[n * LSTR + k0] = *(const uint4*)(Bt + (col0 + n) * D_ + k0);
    }
    __syncthreads();
    const int lane = tid & 63, wave = tid >> 6;
    const int l16 = lane & 15, quad = lane >> 4;
    const int wm = (wave >> 1) * 32, wn = (wave & 1) * 32;
    f32x4 acc[2][2] = {};
#pragma unroll
    for (int kb = 0; kb < 128; kb += 32) {
        bf16x8 a0 = *(bf16x8*)&As[(wm + l16) * LSTR + kb + quad * 8];
        bf16x8 a1 = *(bf16x8*)&As[(wm + 16 + l16) * LSTR + kb + quad * 8];
        bf16x8 b0 = *(bf16x8*)&Bs[(wn + l16) * LSTR + kb + quad * 8];
        bf16x8 b1 = *(bf16x8*)&Bs[(wn + 16 + l16) * LSTR + kb + quad * 8];
        acc[0][0] = __builtin_amdgcn_mfma_f32_16x16x32_bf16(a0, b0, acc[0][0], 0, 0, 0);
        acc[0][1] = __builtin_amdgcn_mfma_f32_16x16x32_bf16(a0, b1, acc[0][1], 0, 0, 0);
        acc[1][0] = __builtin_amdgcn_mfma_f32_16x16x32_bf16(a1, b0, acc[1][0], 0, 0, 0);
        acc[1][1] = __builtin_amdgcn_mfma_f32_16x16x32_bf16(a1, b1, acc[1][1], 0, 0, 0);
    }
#pragma unroll
    for (int j = 0; j < 2; ++j) {
        int gc = col0 + wn + j * 16 + l16;
        float bb = b1l[gc];
#pragma unroll
        for (int i = 0; i < 2; ++i)
#pragma unroll
            for (int r = 0; r < 4; ++r) {
                int gr = row0 + wm + i * 16 + quad * 4 + r;
                if (gr < BN_) T[gr * FF_ + gc] = f2b(fmaxf(acc[i][j][r] + bb, 0.f));
            }
    }
}

// k_ff2: H2 = (H1*sc+sh) + T @ W2T_l^T + b2 ; + BN stats. grid (313,2), K=512
__global__ __launch_bounds__(256) void k_ff2(const unsigned short* __restrict__ T,
                                             const unsigned short* __restrict__ Bt,
                                             const float* __restrict__ H1,
                                             const float* __restrict__ ss,
                                             const float* __restrict__ b2l,
                                             float* __restrict__ H2,
                                             float* __restrict__ part) {
    __shared__ unsigned short As[64 * LSTR];
    __shared__ unsigned short Bs[64 * LSTR];
    const int tid = threadIdx.x;
    const int row0 = blockIdx.x * 64, col0 = blockIdx.y * 64;
    const int lane = tid & 63, wave = tid >> 6;
    const int l16 = lane & 15, quad = lane >> 4;
    const int wm = (wave >> 1) * 32, wn = (wave & 1) * 32;
    f32x4 acc[2][2] = {};
    for (int kc = 0; kc < FF_; kc += 128) {
        if (kc) __syncthreads();
#pragma unroll
        for (int it = 0; it < 4; ++it) {
            int idx = tid + it * 256;
            int m = idx >> 4, k0 = (idx & 15) << 3;
            int gr = row0 + m;
            uint4 w = make_uint4(0u, 0u, 0u, 0u);
            if (gr < BN_) w = *(const uint4*)(T + gr * FF_ + kc + k0);
            *(uint4*)&As[m * LSTR + k0] = w;
        }
#pragma unroll
        for (int it = 0; it < 4; ++it) {
            int idx = tid + it * 256;
            int n = idx >> 4, k0 = (idx & 15) << 3;
            *(uint4*)&Bs[n * LSTR + k0] = *(const uint4*)(Bt + (col0 + n) * FF_ + kc + k0);
        }
        __syncthreads();
#pragma unroll
        for (int kb = 0; kb < 128; kb += 32) {
            bf16x8 a0 = *(bf16x8*)&As[(wm + l16) * LSTR + kb + quad * 8];
            bf16x8 a1 = *(bf16x8*)&As[(wm + 16 + l16) * LSTR + kb + quad * 8];
            bf16x8 b0 = *(bf16x8*)&Bs[(wn + l16) * LSTR + kb + quad * 8];
            bf16x8 b1 = *(bf16x8*)&Bs[(wn + 16 + l16) * LSTR + kb + quad * 8];
            acc[0][0] = __builtin_amdgcn_mfma_f32_16x16x32_bf16(a0, b0, acc[0][0], 0, 0, 0);
            acc[0][1] = __builtin_amdgcn_mfma_f32_16x16x32_bf16(a0, b1, acc[0][1], 0, 0, 0);
            acc[1][0] = __builtin_amdgcn_mfma_f32_16x16x32_bf16(a1, b0, acc[1][0], 0, 0, 0);
            acc[1][1] = __builtin_amdgcn_mfma_f32_16x16x32_bf16(a1, b1, acc[1][1], 0, 0, 0);
        }
    }
    __syncthreads();
    float* Sred = (float*)As;
    float* Qred = (float*)Bs;
    const int slot = (wave >> 1) * 4 + quad;
#pragma unroll
    for (int j = 0; j < 2; ++j) {
        int gc = col0 + wn + j * 16 + l16;
        float sc = ss[gc], sh = ss[128 + gc], bb = b2l[gc];
        float cs = 0.f, cq = 0.f;
#pragma unroll
        for (int i = 0; i < 2; ++i)
#pragma unroll
            for (int r = 0; r < 4; ++r) {
                int gr = row0 + wm + i * 16 + quad * 4 + r;
                if (gr < BN_) {
                    float o = H1[gr * D_ + gc] * sc + sh + acc[i][j][r] + bb;
                    H2[gr * D_ + gc] = o;
                    cs += o; cq += o * o;
                }
            }
        Sred[(wn + j * 16 + l16) * 8 + slot] = cs;
        Qred[(wn + j * 16 + l16) * 8 + slot] = cq;
    }
    __syncthreads();
    if (tid < 64) {
        float s = 0.f, q = 0.f;
#pragma unroll
        for (int t = 0; t < 8; ++t) { s += Sred[tid * 8 + t]; q += Qred[tid * 8 + t]; }
        part[blockIdx.x * 128 + col0 + tid] = s;
        part[NBLK * 128 + blockIdx.x * 128 + col0 + tid] = q;
    }
}

// final: out = H2*scale + shift
__global__ __launch_bounds__(256) void k_apply(const float4* __restrict__ H2,
                                               const float* __restrict__ ss,
                                               float4* __restrict__ out) {
    int i = blockIdx.x * 256 + threadIdx.x;
    if (i >= BN_ * D_ / 4) return;
    int c = (i & 31) << 2;
    float4 v = H2[i];
    v.x = v.x * ss[c + 0] + ss[128 + c + 0];
    v.y = v.y * ss[c + 1] + ss[128 + c + 1];
    v.z = v.z * ss[c + 2] + ss[128 + c + 2];
    v.w = v.w * ss[c + 3] + ss[128 + c + 3];
    out[i] = v;
}

// ---------------- launch ----------------

extern "C" void kernel_launch(void* const* d_in, const int* in_sizes, int n_in,
                              void* d_out, int out_size, void* d_ws, size_t ws_size,
                              hipStream_t stream) {
    (void)in_sizes; (void)n_in; (void)out_size; (void)ws_size;
    const float* x    = (const float*)d_in[0];
    const int*   edge = (const int*)d_in[1];
    const float* Wv   = (const float*)d_in[4];
    const float* Wout = (const float*)d_in[5];
    const float* bn1w = (const float*)d_in[6];
    const float* bn1b = (const float*)d_in[7];
    const float* W1   = (const float*)d_in[8];
    const float* b1   = (const float*)d_in[9];
    const float* W2   = (const float*)d_in[10];
    const float* b2   = (const float*)d_in[11];
    const float* bn2w = (const float*)d_in[12];
    const float* bn2b = (const float*)d_in[13];

    float* ws    = (float*)d_ws;
    float* bufA  = ws;                    // 2,560,000 (H2)
    float* bufB  = ws + 2560000;          // 2,560,000 (H1)
    float* flag  = ws + 5120000;          // 20,000
    float* part  = ws + 5140000;          // 80,128
    float* ss_id = ws + 5220128;          // 256
    float* ssA   = ws + 5220384;          // 256
    float* ssB   = ws + 5220640;          // 256
    unsigned short* Vs  = (unsigned short*)(ws + 5221000);   // 2.56M us
    unsigned short* T   = (unsigned short*)(ws + 6501000);   // 10.24M us
    unsigned short* WcT = (unsigned short*)(ws + 11621000);  // 49152 us
    unsigned short* WoT = (unsigned short*)(ws + 11645576);  // 49152 us
    unsigned short* W1T = (unsigned short*)(ws + 11670152);  // 196608 us
    unsigned short* W2T = (unsigned short*)(ws + 11768456);  // 196608 us
    // total ~11.87M floats ~47.5 MiB

    k_wvt<<<192, 256, 0, stream>>>(Wv, WcT);
    k_tr<<<192, 256, 0, stream>>>(Wout, WoT, 128, 128, 49152);
    k_tr<<<768, 256, 0, stream>>>(W1, W1T, 128, 512, 196608);
    k_tr<<<768, 256, 0, stream>>>(W2, W2T, 512, 128, 196608);
    k_init_ss<<<79, 256, 0, stream>>>(ss_id, flag);
    k_flag<<<1250, 256, 0, stream>>>(edge + E_, flag);

    for (int l = 0; l < 3; ++l) {
        const float* Hc  = (l == 0) ? x : bufA;
        const float* ssp = (l == 0) ? ss_id : ssB;
        k_vs<<<dim3(NBLK, 2), 256, 0, stream>>>(Hc, ssp, WcT + l * 16384, Vs);
        k_out<<<dim3(NBLK, 2), 256, 0, stream>>>(Vs, WoT + l * 16384, Hc, ssp,
                                                 flag, bufB, part);
        k_bnfin<<<1, 128, 0, stream>>>(part, bn1w + l * 128, bn1b + l * 128, ssA);
        k_ff1<<<dim3(NBLK, 8), 256, 0, stream>>>(bufB, ssA, W1T + l * 65536,
                                                 b1 + l * 512, T);
        k_ff2<<<dim3(NBLK, 2), 256, 0, stream>>>(T, W2T + l * 65536, bufB, ssA,
                                                 b2 + l * 128, bufA, part);
        k_bnfin<<<1, 128, 0, stream>>>(part, bn2w + l * 128, bn2b + l * 128, ssB);
    }
    k_apply<<<2500, 256, 0, stream>>>((const float4*)bufA, ssB, (float4*)d_out);
}

// Round 6
// 297.888 us; speedup vs baseline: 2.1899x; 1.4690x over previous
//
#include <hip/hip_runtime.h>
#include <hip/hip_bf16.h>

#define BN_ 20000
#define D_ 128
#define FF_ 512
#define E_ 320000
#define NBLK 313   // ceil(20000/64)
#define LSTR 136   // LDS row stride in bf16 elems (128 + 8 pad; 272 B, 16B-aligned)

typedef __attribute__((ext_vector_type(8))) short bf16x8;
typedef __attribute__((ext_vector_type(4))) float f32x4;

__device__ __forceinline__ unsigned short f2b(float f) {
    unsigned int u = __float_as_uint(f);
    u = (u + 0x7FFFu + ((u >> 16) & 1u)) >> 16;
    return (unsigned short)u;
}

// recompute BN scale/shift from atomically-accumulated column sums
__device__ __forceinline__ void make_ss(const float* __restrict__ acc,
                                        const float* __restrict__ w,
                                        const float* __restrict__ b,
                                        float* __restrict__ ss_sh, int tid) {
    if (tid < 128) {
        if (acc) {
            float s = acc[tid], q = acc[128 + tid];
            float mu  = s * (1.f / 20000.f);
            float var = fmaxf(q * (1.f / 20000.f) - mu * mu, 0.f);
            float rstd  = rsqrtf(var + 1e-5f);
            float scale = w[tid] * rstd;
            ss_sh[tid]       = scale;
            ss_sh[128 + tid] = b[tid] - mu * scale;
        } else {
            ss_sh[tid]       = 1.f;
            ss_sh[128 + tid] = 0.f;
        }
    }
}

// ---------------- prep ----------------
// all weight transposes (fp32 -> bf16 [n][k]) + flag zeroing, one kernel
__global__ __launch_bounds__(256) void k_prep(const float* __restrict__ Wv,
                                              const float* __restrict__ Wout,
                                              const float* __restrict__ W1,
                                              const float* __restrict__ W2,
                                              unsigned short* __restrict__ WcT,
                                              unsigned short* __restrict__ WoT,
                                              unsigned short* __restrict__ W1T,
                                              unsigned short* __restrict__ W2T,
                                              float* __restrict__ flag) {
    int idx = blockIdx.x * 256 + threadIdx.x;
    if (idx < 49152) {                       // WcT[l][n=h*16+kk][k=d]
        int l = idx / 16384, r = idx % 16384;
        int n = r >> 7, k = r & 127;
        int h = n >> 4, kk = n & 15;
        WcT[idx] = f2b(Wv[((l * 8 + h) * 128 + k) * 16 + kk]);
        return;
    }
    idx -= 49152;
    if (idx < 49152) {                       // WoT[l][n][k], K=N=128
        int l = idx / 16384, r = idx % 16384;
        int n = r >> 7, k = r & 127;
        WoT[idx] = f2b(Wout[l * 16384 + k * 128 + n]);
        return;
    }
    idx -= 49152;
    if (idx < 196608) {                      // W1T[l][n][k], K=128,N=512
        int l = idx / 65536, r = idx % 65536;
        int n = r >> 7, k = r & 127;
        W1T[idx] = f2b(W1[l * 65536 + k * 512 + n]);
        return;
    }
    idx -= 196608;
    if (idx < 196608) {                      // W2T[l][n][k], K=512,N=128
        int l = idx / 65536, r = idx % 65536;
        int n = r / 512, k = r % 512;
        W2T[idx] = f2b(W2[l * 65536 + k * 128 + n]);
        return;
    }
    idx -= 196608;
    if (idx < 20000) flag[idx] = 0.f;
}

__global__ __launch_bounds__(256) void k_flag(const int* __restrict__ dst,
                                              float* __restrict__ flag) {
    int e = blockIdx.x * 256 + threadIdx.x;
    if (e < E_) flag[dst[e]] = 1.0f;
}

// ---------------- MFMA GEMM kernels ----------------
// 256 thr = 4 waves (2x2), tile 64x64, K-chunk 128 in LDS.
// A[m=lane&15][k=quad*8+j]; B[k][n=lane&15]; D col=lane&15,row=quad*4+reg.

// k_vs: Vs([H][BN][16], bf16) = (H*sc+sh) @ WcatT^T ; zeroes accA. grid (313,2)
__global__ __launch_bounds__(256) void k_vs(const float* __restrict__ H,
                                            const float* __restrict__ accP,
                                            const float* __restrict__ bnw,
                                            const float* __restrict__ bnb,
                                            const unsigned short* __restrict__ Bt,
                                            unsigned short* __restrict__ Vs,
                                            float* __restrict__ accZ) {
    __shared__ unsigned short As[64 * LSTR];
    __shared__ unsigned short Bs[64 * LSTR];
    __shared__ float ss_sh[256];
    const int tid = threadIdx.x;
    const int row0 = blockIdx.x * 64, col0 = blockIdx.y * 64;
    make_ss(accP, bnw, bnb, ss_sh, tid);
    if (blockIdx.x == 0 && blockIdx.y == 0) accZ[tid] = 0.f;
    __syncthreads();
#pragma unroll
    for (int it = 0; it < 4; ++it) {
        int idx = tid + it * 256;
        int m = idx >> 4, k0 = (idx & 15) << 3;
        int gr = row0 + m;
        float v[8];
        if (gr < BN_) {
            f32x4 v0 = *(const f32x4*)(H + gr * D_ + k0);
            f32x4 v1 = *(const f32x4*)(H + gr * D_ + k0 + 4);
            v[0] = v0.x; v[1] = v0.y; v[2] = v0.z; v[3] = v0.w;
            v[4] = v1.x; v[5] = v1.y; v[6] = v1.z; v[7] = v1.w;
        } else {
#pragma unroll
            for (int j = 0; j < 8; ++j) v[j] = 0.f;
        }
        unsigned int p[4];
#pragma unroll
        for (int j = 0; j < 4; ++j) {
            unsigned short lo = f2b(v[2 * j] * ss_sh[k0 + 2 * j] + ss_sh[128 + k0 + 2 * j]);
            unsigned short hi = f2b(v[2 * j + 1] * ss_sh[k0 + 2 * j + 1] + ss_sh[128 + k0 + 2 * j + 1]);
            p[j] = (unsigned int)lo | ((unsigned int)hi << 16);
        }
        *(uint4*)&As[m * LSTR + k0] = make_uint4(p[0], p[1], p[2], p[3]);
    }
#pragma unroll
    for (int it = 0; it < 4; ++it) {
        int idx = tid + it * 256;
        int n = idx >> 4, k0 = (idx & 15) << 3;
        *(uint4*)&Bs[n * LSTR + k0] = *(const uint4*)(Bt + (col0 + n) * D_ + k0);
    }
    __syncthreads();
    const int lane = tid & 63, wave = tid >> 6;
    const int l16 = lane & 15, quad = lane >> 4;
    const int wm = (wave >> 1) * 32, wn = (wave & 1) * 32;
    f32x4 acc[2][2] = {};
#pragma unroll
    for (int kb = 0; kb < 128; kb += 32) {
        bf16x8 a0 = *(bf16x8*)&As[(wm + l16) * LSTR + kb + quad * 8];
        bf16x8 a1 = *(bf16x8*)&As[(wm + 16 + l16) * LSTR + kb + quad * 8];
        bf16x8 b0 = *(bf16x8*)&Bs[(wn + l16) * LSTR + kb + quad * 8];
        bf16x8 b1 = *(bf16x8*)&Bs[(wn + 16 + l16) * LSTR + kb + quad * 8];
        acc[0][0] = __builtin_amdgcn_mfma_f32_16x16x32_bf16(a0, b0, acc[0][0], 0, 0, 0);
        acc[0][1] = __builtin_amdgcn_mfma_f32_16x16x32_bf16(a0, b1, acc[0][1], 0, 0, 0);
        acc[1][0] = __builtin_amdgcn_mfma_f32_16x16x32_bf16(a1, b0, acc[1][0], 0, 0, 0);
        acc[1][1] = __builtin_amdgcn_mfma_f32_16x16x32_bf16(a1, b1, acc[1][1], 0, 0, 0);
    }
#pragma unroll
    for (int i = 0; i < 2; ++i)
#pragma unroll
        for (int j = 0; j < 2; ++j) {
            int gc = col0 + wn + j * 16 + l16;
            int h = gc >> 4, kk = gc & 15;
#pragma unroll
            for (int r = 0; r < 4; ++r) {
                int gr = row0 + wm + i * 16 + quad * 4 + r;
                if (gr < BN_) Vs[h * (BN_ * 16) + gr * 16 + kk] = f2b(acc[i][j][r]);
            }
        }
}

// k_out: H1 = z + flag.*(VsFlat @ WoutT^T), z = H*sc+sh ; atomics -> accA. grid (313,2)
__global__ __launch_bounds__(256) void k_out(const unsigned short* __restrict__ Vs,
                                             const unsigned short* __restrict__ Bt,
                                             const float* __restrict__ H,
                                             const float* __restrict__ accP,
                                             const float* __restrict__ bnw,
                                             const float* __restrict__ bnb,
                                             const float* __restrict__ flag,
                                             float* __restrict__ H1,
                                             float* __restrict__ accA) {
    __shared__ unsigned short As[64 * LSTR];
    __shared__ unsigned short Bs[64 * LSTR];
    __shared__ float ss_sh[256];
    const int tid = threadIdx.x;
    const int row0 = blockIdx.x * 64, col0 = blockIdx.y * 64;
    make_ss(accP, bnw, bnb, ss_sh, tid);
#pragma unroll
    for (int it = 0; it < 4; ++it) {
        int idx = tid + it * 256;
        int m = idx >> 4, k0 = (idx & 15) << 3;
        int gr = row0 + m;
        uint4 w = make_uint4(0u, 0u, 0u, 0u);
        if (gr < BN_) w = *(const uint4*)(Vs + gr * D_ + k0);
        *(uint4*)&As[m * LSTR + k0] = w;
    }
#pragma unroll
    for (int it = 0; it < 4; ++it) {
        int idx = tid + it * 256;
        int n = idx >> 4, k0 = (idx & 15) << 3;
        *(uint4*)&Bs[n * LSTR + k0] = *(const uint4*)(Bt + (col0 + n) * D_ + k0);
    }
    __syncthreads();
    const int lane = tid & 63, wave = tid >> 6;
    const int l16 = lane & 15, quad = lane >> 4;
    const int wm = (wave >> 1) * 32, wn = (wave & 1) * 32;
    f32x4 acc[2][2] = {};
#pragma unroll
    for (int kb = 0; kb < 128; kb += 32) {
        bf16x8 a0 = *(bf16x8*)&As[(wm + l16) * LSTR + kb + quad * 8];
        bf16x8 a1 = *(bf16x8*)&As[(wm + 16 + l16) * LSTR + kb + quad * 8];
        bf16x8 b0 = *(bf16x8*)&Bs[(wn + l16) * LSTR + kb + quad * 8];
        bf16x8 b1 = *(bf16x8*)&Bs[(wn + 16 + l16) * LSTR + kb + quad * 8];
        acc[0][0] = __builtin_amdgcn_mfma_f32_16x16x32_bf16(a0, b0, acc[0][0], 0, 0, 0);
        acc[0][1] = __builtin_amdgcn_mfma_f32_16x16x32_bf16(a0, b1, acc[0][1], 0, 0, 0);
        acc[1][0] = __builtin_amdgcn_mfma_f32_16x16x32_bf16(a1, b0, acc[1][0], 0, 0, 0);
        acc[1][1] = __builtin_amdgcn_mfma_f32_16x16x32_bf16(a1, b1, acc[1][1], 0, 0, 0);
    }
    __syncthreads();   // LDS reuse for stats
    float* Sred = (float*)As;  // [64][8]
    float* Qred = (float*)Bs;
    const int slot = (wave >> 1) * 4 + quad;
#pragma unroll
    for (int j = 0; j < 2; ++j) {
        int gc = col0 + wn + j * 16 + l16;
        float sc = ss_sh[gc - col0 + ((gc >= col0) ? 0 : 0)];  // placeholder
        sc = ss_sh[(gc & 127)];
        float sh = ss_sh[128 + (gc & 127)];
        float cs = 0.f, cq = 0.f;
#pragma unroll
        for (int i = 0; i < 2; ++i)
#pragma unroll
            for (int r = 0; r < 4; ++r) {
                int gr = row0 + wm + i * 16 + quad * 4 + r;
                if (gr < BN_) {
                    float z = H[gr * D_ + gc] * sc + sh;
                    float o = z + flag[gr] * acc[i][j][r];
                    H1[gr * D_ + gc] = o;
                    cs += o; cq += o * o;
                }
            }
        Sred[(wn + j * 16 + l16) * 8 + slot] = cs;
        Qred[(wn + j * 16 + l16) * 8 + slot] = cq;
    }
    __syncthreads();
    if (tid < 64) {
        float s = 0.f, q = 0.f;
#pragma unroll
        for (int t = 0; t < 8; ++t) { s += Sred[tid * 8 + t]; q += Qred[tid * 8 + t]; }
        atomicAdd(&accA[col0 + tid], s);
        atomicAdd(&accA[128 + col0 + tid], q);
    }
}

// k_ff1: T(bf16) = relu((H1*sc+sh) @ W1T^T + b1) ; zeroes accB. grid (313,8)
__global__ __launch_bounds__(256) void k_ff1(const float* __restrict__ H1,
                                             const float* __restrict__ accA,
                                             const float* __restrict__ bnw,
                                             const float* __restrict__ bnb,
                                             const unsigned short* __restrict__ Bt,
                                             const float* __restrict__ b1l,
                                             unsigned short* __restrict__ T,
                                             float* __restrict__ accZ) {
    __shared__ unsigned short As[64 * LSTR];
    __shared__ unsigned short Bs[64 * LSTR];
    __shared__ float ss_sh[256];
    const int tid = threadIdx.x;
    const int row0 = blockIdx.x * 64, col0 = blockIdx.y * 64;
    make_ss(accA, bnw, bnb, ss_sh, tid);
    if (blockIdx.x == 0 && blockIdx.y == 0) accZ[tid] = 0.f;
    __syncthreads();
#pragma unroll
    for (int it = 0; it < 4; ++it) {
        int idx = tid + it * 256;
        int m = idx >> 4, k0 = (idx & 15) << 3;
        int gr = row0 + m;
        float v[8];
        if (gr < BN_) {
            f32x4 v0 = *(const f32x4*)(H1 + gr * D_ + k0);
            f32x4 v1 = *(const f32x4*)(H1 + gr * D_ + k0 + 4);
            v[0] = v0.x; v[1] = v0.y; v[2] = v0.z; v[3] = v0.w;
            v[4] = v1.x; v[5] = v1.y; v[6] = v1.z; v[7] = v1.w;
        } else {
#pragma unroll
            for (int j = 0; j < 8; ++j) v[j] = 0.f;
        }
        unsigned int p[4];
#pragma unroll
        for (int j = 0; j < 4; ++j) {
            unsigned short lo = f2b(v[2 * j] * ss_sh[k0 + 2 * j] + ss_sh[128 + k0 + 2 * j]);
            unsigned short hi = f2b(v[2 * j + 1] * ss_sh[k0 + 2 * j + 1] + ss_sh[128 + k0 + 2 * j + 1]);
            p[j] = (unsigned int)lo | ((unsigned int)hi << 16);
        }
        *(uint4*)&As[m * LSTR + k0] = make_uint4(p[0], p[1], p[2], p[3]);
    }
#pragma unroll
    for (int it = 0; it < 4; ++it) {
        int idx = tid + it * 256;
        int n = idx >> 4, k0 = (idx & 15) << 3;
        *(uint4*)&Bs[n * LSTR + k0] = *(const uint4*)(Bt + (col0 + n) * D_ + k0);
    }
    __syncthreads();
    const int lane = tid & 63, wave = tid >> 6;
    const int l16 = lane & 15, quad = lane >> 4;
    const int wm = (wave >> 1) * 32, wn = (wave & 1) * 32;
    f32x4 acc[2][2] = {};
#pragma unroll
    for (int kb = 0; kb < 128; kb += 32) {
        bf16x8 a0 = *(bf16x8*)&As[(wm + l16) * LSTR + kb + quad * 8];
        bf16x8 a1 = *(bf16x8*)&As[(wm + 16 + l16) * LSTR + kb + quad * 8];
        bf16x8 b0 = *(bf16x8*)&Bs[(wn + l16) * LSTR + kb + quad * 8];
        bf16x8 b1 = *(bf16x8*)&Bs[(wn + 16 + l16) * LSTR + kb + quad * 8];
        acc[0][0] = __builtin_amdgcn_mfma_f32_16x16x32_bf16(a0, b0, acc[0][0], 0, 0, 0);
        acc[0][1] = __builtin_amdgcn_mfma_f32_16x16x32_bf16(a0, b1, acc[0][1], 0, 0, 0);
        acc[1][0] = __builtin_amdgcn_mfma_f32_16x16x32_bf16(a1, b0, acc[1][0], 0, 0, 0);
        acc[1][1] = __builtin_amdgcn_mfma_f32_16x16x32_bf16(a1, b1, acc[1][1], 0, 0, 0);
    }
#pragma unroll
    for (int j = 0; j < 2; ++j) {
        int gc = col0 + wn + j * 16 + l16;
        float bb = b1l[gc];
#pragma unroll
        for (int i = 0; i < 2; ++i)
#pragma unroll
            for (int r = 0; r < 4; ++r) {
                int gr = row0 + wm + i * 16 + quad * 4 + r;
                if (gr < BN_) T[gr * FF_ + gc] = f2b(fmaxf(acc[i][j][r] + bb, 0.f));
            }
    }
}

// k_ff2: H2 = (H1*sc+sh) + T @ W2T^T + b2 ; atomics -> accB. grid (313,2), K=512
__global__ __launch_bounds__(256) void k_ff2(const unsigned short* __restrict__ T,
                                             const unsigned short* __restrict__ Bt,
                                             const float* __restrict__ H1,
                                             const float* __restrict__ accA,
                                             const float* __restrict__ bnw,
                                             const float* __restrict__ bnb,
                                             const float* __restrict__ b2l,
                                             float* __restrict__ H2,
                                             float* __restrict__ accB) {
    __shared__ unsigned short As[64 * LSTR];
    __shared__ unsigned short Bs[64 * LSTR];
    __shared__ float ss_sh[256];
    const int tid = threadIdx.x;
    const int row0 = blockIdx.x * 64, col0 = blockIdx.y * 64;
    const int lane = tid & 63, wave = tid >> 6;
    const int l16 = lane & 15, quad = lane >> 4;
    const int wm = (wave >> 1) * 32, wn = (wave & 1) * 32;
    make_ss(accA, bnw, bnb, ss_sh, tid);
    f32x4 acc[2][2] = {};
    for (int kc = 0; kc < FF_; kc += 128) {
        if (kc) __syncthreads();
#pragma unroll
        for (int it = 0; it < 4; ++it) {
            int idx = tid + it * 256;
            int m = idx >> 4, k0 = (idx & 15) << 3;
            int gr = row0 + m;
            uint4 w = make_uint4(0u, 0u, 0u, 0u);
            if (gr < BN_) w = *(const uint4*)(T + gr * FF_ + kc + k0);
            *(uint4*)&As[m * LSTR + k0] = w;
        }
#pragma unroll
        for (int it = 0; it < 4; ++it) {
            int idx = tid + it * 256;
            int n = idx >> 4, k0 = (idx & 15) << 3;
            *(uint4*)&Bs[n * LSTR + k0] = *(const uint4*)(Bt + (col0 + n) * FF_ + kc + k0);
        }
        __syncthreads();
#pragma unroll
        for (int kb = 0; kb < 128; kb += 32) {
            bf16x8 a0 = *(bf16x8*)&As[(wm + l16) * LSTR + kb + quad * 8];
            bf16x8 a1 = *(bf16x8*)&As[(wm + 16 + l16) * LSTR + kb + quad * 8];
            bf16x8 b0 = *(bf16x8*)&Bs[(wn + l16) * LSTR + kb + quad * 8];
            bf16x8 b1 = *(bf16x8*)&Bs[(wn + 16 + l16) * LSTR + kb + quad * 8];
            acc[0][0] = __builtin_amdgcn_mfma_f32_16x16x32_bf16(a0, b0, acc[0][0], 0, 0, 0);
            acc[0][1] = __builtin_amdgcn_mfma_f32_16x16x32_bf16(a0, b1, acc[0][1], 0, 0, 0);
            acc[1][0] = __builtin_amdgcn_mfma_f32_16x16x32_bf16(a1, b0, acc[1][0], 0, 0, 0);
            acc[1][1] = __builtin_amdgcn_mfma_f32_16x16x32_bf16(a1, b1, acc[1][1], 0, 0, 0);
        }
    }
    __syncthreads();
    float* Sred = (float*)As;
    float* Qred = (float*)Bs;
    const int slot = (wave >> 1) * 4 + quad;
#pragma unroll
    for (int j = 0; j < 2; ++j) {
        int gc = col0 + wn + j * 16 + l16;
        float sc = ss_sh[gc & 127], sh = ss_sh[128 + (gc & 127)], bb = b2l[gc];
        float cs = 0.f, cq = 0.f;
#pragma unroll
        for (int i = 0; i < 2; ++i)
#pragma unroll
            for (int r = 0; r < 4; ++r) {
                int gr = row0 + wm + i * 16 + quad * 4 + r;
                if (gr < BN_) {
                    float o = H1[gr * D_ + gc] * sc + sh + acc[i][j][r] + bb;
                    H2[gr * D_ + gc] = o;
                    cs += o; cq += o * o;
                }
            }
        Sred[(wn + j * 16 + l16) * 8 + slot] = cs;
        Qred[(wn + j * 16 + l16) * 8 + slot] = cq;
    }
    __syncthreads();
    if (tid < 64) {
        float s = 0.f, q = 0.f;
#pragma unroll
        for (int t = 0; t < 8; ++t) { s += Sred[tid * 8 + t]; q += Qred[tid * 8 + t]; }
        atomicAdd(&accB[col0 + tid], s);
        atomicAdd(&accB[128 + col0 + tid], q);
    }
}

// final: out = H2*scale + shift, ss recomputed per block from accB
__global__ __launch_bounds__(256) void k_apply(const float4* __restrict__ H2,
                                               const float* __restrict__ accB,
                                               const float* __restrict__ bnw,
                                               const float* __restrict__ bnb,
                                               float4* __restrict__ out) {
    __shared__ float ss_sh[256];
    make_ss(accB, bnw, bnb, ss_sh, threadIdx.x);
    __syncthreads();
    int i = blockIdx.x * 256 + threadIdx.x;
    if (i >= BN_ * D_ / 4) return;
    int c = (i & 31) << 2;
    float4 v = H2[i];
    v.x = v.x * ss_sh[c + 0] + ss_sh[128 + c + 0];
    v.y = v.y * ss_sh[c + 1] + ss_sh[128 + c + 1];
    v.z = v.z * ss_sh[c + 2] + ss_sh[128 + c + 2];
    v.w = v.w * ss_sh[c + 3] + ss_sh[128 + c + 3];
    out[i] = v;
}

// ---------------- launch ----------------

extern "C" void kernel_launch(void* const* d_in, const int* in_sizes, int n_in,
                              void* d_out, int out_size, void* d_ws, size_t ws_size,
                              hipStream_t stream) {
    (void)in_sizes; (void)n_in; (void)out_size; (void)ws_size;
    const float* x    = (const float*)d_in[0];
    const int*   edge = (const int*)d_in[1];
    const float* Wv   = (const float*)d_in[4];
    const float* Wout = (const float*)d_in[5];
    const float* bn1w = (const float*)d_in[6];
    const float* bn1b = (const float*)d_in[7];
    const float* W1   = (const float*)d_in[8];
    const float* b1   = (const float*)d_in[9];
    const float* W2   = (const float*)d_in[10];
    const float* b2   = (const float*)d_in[11];
    const float* bn2w = (const float*)d_in[12];
    const float* bn2b = (const float*)d_in[13];

    float* ws   = (float*)d_ws;
    float* bufA = ws;                    // 2,560,000 (H2)
    float* bufB = ws + 2560000;          // 2,560,000 (H1)
    float* flag = ws + 5120000;          // 20,000
    float* accA = ws + 5140000;          // 256
    float* accB = ws + 5140256;          // 256
    unsigned short* Vs  = (unsigned short*)(ws + 5140512);   // 2.56M us
    unsigned short* T   = (unsigned short*)(ws + 6420512);   // 10.24M us
    unsigned short* WcT = (unsigned short*)(ws + 11540512);  // 49152 us
    unsigned short* WoT = (unsigned short*)(ws + 11565088);  // 49152 us
    unsigned short* W1T = (unsigned short*)(ws + 11589664);  // 196608 us
    unsigned short* W2T = (unsigned short*)(ws + 11687968);  // 196608 us
    // total ~11.79M floats ~47.2 MiB

    k_prep<<<1999, 256, 0, stream>>>(Wv, Wout, W1, W2, WcT, WoT, W1T, W2T, flag);
    k_flag<<<1250, 256, 0, stream>>>(edge + E_, flag);

    for (int l = 0; l < 3; ++l) {
        const float* Hc   = (l == 0) ? x : bufA;
        const float* accP = (l == 0) ? nullptr : accB;
        const float* bw   = bn2w + (l ? (l - 1) * 128 : 0);
        const float* bbv  = bn2b + (l ? (l - 1) * 128 : 0);
        k_vs<<<dim3(NBLK, 2), 256, 0, stream>>>(Hc, accP, bw, bbv,
                                                WcT + l * 16384, Vs, accA);
        k_out<<<dim3(NBLK, 2), 256, 0, stream>>>(Vs, WoT + l * 16384, Hc, accP,
                                                 bw, bbv, flag, bufB, accA);
        k_ff1<<<dim3(NBLK, 8), 256, 0, stream>>>(bufB, accA, bn1w + l * 128,
                                                 bn1b + l * 128, W1T + l * 65536,
                                                 b1 + l * 512, T, accB);
        k_ff2<<<dim3(NBLK, 2), 256, 0, stream>>>(T, W2T + l * 65536, bufB, accA,
                                                 bn1w + l * 128, bn1b + l * 128,
                                                 b2 + l * 128, bufA, accB);
    }
    k_apply<<<2500, 256, 0, stream>>>((const float4*)bufA, accB, bn2w + 256,
                                      bn2b + 256, (float4*)d_out);
}

// Round 8
// 251.404 us; speedup vs baseline: 2.5948x; 1.1849x over previous
//
#include <hip/hip_runtime.h>
#include <hip/hip_bf16.h>

#define BN_ 20000
#define D_ 128
#define FF_ 512
#define E_ 320000
#define NBLK 313   // ceil(20000/64)
#define LSTR 136   // LDS row stride (bf16) for 128-wide tiles
#define TSTR 72    // LDS row stride (bf16) for 64-wide T chunk
#define B2STR 72   // LDS row stride (bf16) for W2T chunk [128][64]

typedef __attribute__((ext_vector_type(8))) short bf16x8;
typedef __attribute__((ext_vector_type(4))) float f32x4;

__device__ __forceinline__ unsigned short f2b(float f) {
    unsigned int u = __float_as_uint(f);
    u = (u + 0x7FFFu + ((u >> 16) & 1u)) >> 16;
    return (unsigned short)u;
}

// recompute BN scale/shift from atomically-accumulated column sums
__device__ __forceinline__ void make_ss(const float* __restrict__ acc,
                                        const float* __restrict__ w,
                                        const float* __restrict__ b,
                                        float* __restrict__ ss_sh, int tid) {
    if (tid < 128) {
        if (acc) {
            float s = acc[tid], q = acc[128 + tid];
            float mu  = s * (1.f / 20000.f);
            float var = fmaxf(q * (1.f / 20000.f) - mu * mu, 0.f);
            float rstd  = rsqrtf(var + 1e-5f);
            float scale = w[tid] * rstd;
            ss_sh[tid]       = scale;
            ss_sh[128 + tid] = b[tid] - mu * scale;
        } else {
            ss_sh[tid]       = 1.f;
            ss_sh[128 + tid] = 0.f;
        }
    }
}

// ---------------- prep ----------------
// weight transposes (fp32 -> bf16 [n][k]) + flag zeroing + acc zeroing
__global__ __launch_bounds__(256) void k_prep(const float* __restrict__ Wv,
                                              const float* __restrict__ Wout,
                                              const float* __restrict__ W1,
                                              const float* __restrict__ W2,
                                              unsigned short* __restrict__ WcT,
                                              unsigned short* __restrict__ WoT,
                                              unsigned short* __restrict__ W1T,
                                              unsigned short* __restrict__ W2T,
                                              float* __restrict__ flag,
                                              float* __restrict__ acc6) {
    int idx = blockIdx.x * 256 + threadIdx.x;
    if (idx < 49152) {                       // WcT[l][n=h*16+kk][k=d]
        int l = idx / 16384, r = idx % 16384;
        int n = r >> 7, k = r & 127;
        int h = n >> 4, kk = n & 15;
        WcT[idx] = f2b(Wv[((l * 8 + h) * 128 + k) * 16 + kk]);
        return;
    }
    idx -= 49152;
    if (idx < 49152) {                       // WoT[l][n][k], K=N=128
        int l = idx / 16384, r = idx % 16384;
        int n = r >> 7, k = r & 127;
        WoT[idx] = f2b(Wout[l * 16384 + k * 128 + n]);
        return;
    }
    idx -= 49152;
    if (idx < 196608) {                      // W1T[l][n][k], K=128,N=512
        int l = idx / 65536, r = idx % 65536;
        int n = r >> 7, k = r & 127;
        W1T[idx] = f2b(W1[l * 65536 + k * 512 + n]);
        return;
    }
    idx -= 196608;
    if (idx < 196608) {                      // W2T[l][n][k], K=512,N=128
        int l = idx / 65536, r = idx % 65536;
        int n = r / 512, k = r % 512;
        W2T[idx] = f2b(W2[l * 65536 + k * 128 + n]);
        return;
    }
    idx -= 196608;
    if (idx < 20000) { flag[idx] = 0.f; return; }
    idx -= 20000;
    if (idx < 1536) acc6[idx] = 0.f;         // 6 x 256 BN accumulators
}

__global__ __launch_bounds__(256) void k_flag(const int* __restrict__ dst,
                                              float* __restrict__ flag) {
    int e = blockIdx.x * 256 + threadIdx.x;
    if (e < E_) flag[dst[e]] = 1.0f;
}

// ---------------- MFMA GEMM kernels ----------------
// A[m=lane&15][k=quad*8+j]; B[k][n=lane&15]; D col=lane&15,row=quad*4+reg.

// k_vs: Vs([H][BN][16], bf16) = (H*sc+sh) @ WcatT^T ; grid (313,2)
__global__ __launch_bounds__(256) void k_vs(const float* __restrict__ H,
                                            const float* __restrict__ accP,
                                            const float* __restrict__ bnw,
                                            const float* __restrict__ bnb,
                                            const unsigned short* __restrict__ Bt,
                                            unsigned short* __restrict__ Vs) {
    __shared__ unsigned short As[64 * LSTR];
    __shared__ unsigned short Bs[64 * LSTR];
    __shared__ float ss_sh[256];
    const int tid = threadIdx.x;
    const int row0 = blockIdx.x * 64, col0 = blockIdx.y * 64;
    make_ss(accP, bnw, bnb, ss_sh, tid);
    __syncthreads();
#pragma unroll
    for (int it = 0; it < 4; ++it) {
        int idx = tid + it * 256;
        int m = idx >> 4, k0 = (idx & 15) << 3;
        int gr = row0 + m;
        float v[8];
        if (gr < BN_) {
            f32x4 v0 = *(const f32x4*)(H + gr * D_ + k0);
            f32x4 v1 = *(const f32x4*)(H + gr * D_ + k0 + 4);
            v[0] = v0.x; v[1] = v0.y; v[2] = v0.z; v[3] = v0.w;
            v[4] = v1.x; v[5] = v1.y; v[6] = v1.z; v[7] = v1.w;
        } else {
#pragma unroll
            for (int j = 0; j < 8; ++j) v[j] = 0.f;
        }
        unsigned int p[4];
#pragma unroll
        for (int j = 0; j < 4; ++j) {
            unsigned short lo = f2b(v[2 * j] * ss_sh[k0 + 2 * j] + ss_sh[128 + k0 + 2 * j]);
            unsigned short hi = f2b(v[2 * j + 1] * ss_sh[k0 + 2 * j + 1] + ss_sh[128 + k0 + 2 * j + 1]);
            p[j] = (unsigned int)lo | ((unsigned int)hi << 16);
        }
        *(uint4*)&As[m * LSTR + k0] = make_uint4(p[0], p[1], p[2], p[3]);
    }
#pragma unroll
    for (int it = 0; it < 4; ++it) {
        int idx = tid + it * 256;
        int n = idx >> 4, k0 = (idx & 15) << 3;
        *(uint4*)&Bs[n * LSTR + k0] = *(const uint4*)(Bt + (col0 + n) * D_ + k0);
    }
    __syncthreads();
    const int lane = tid & 63, wave = tid >> 6;
    const int l16 = lane & 15, quad = lane >> 4;
    const int wm = (wave >> 1) * 32, wn = (wave & 1) * 32;
    f32x4 acc[2][2] = {};
#pragma unroll
    for (int kb = 0; kb < 128; kb += 32) {
        bf16x8 a0 = *(bf16x8*)&As[(wm + l16) * LSTR + kb + quad * 8];
        bf16x8 a1 = *(bf16x8*)&As[(wm + 16 + l16) * LSTR + kb + quad * 8];
        bf16x8 b0 = *(bf16x8*)&Bs[(wn + l16) * LSTR + kb + quad * 8];
        bf16x8 b1 = *(bf16x8*)&Bs[(wn + 16 + l16) * LSTR + kb + quad * 8];
        acc[0][0] = __builtin_amdgcn_mfma_f32_16x16x32_bf16(a0, b0, acc[0][0], 0, 0, 0);
        acc[0][1] = __builtin_amdgcn_mfma_f32_16x16x32_bf16(a0, b1, acc[0][1], 0, 0, 0);
        acc[1][0] = __builtin_amdgcn_mfma_f32_16x16x32_bf16(a1, b0, acc[1][0], 0, 0, 0);
        acc[1][1] = __builtin_amdgcn_mfma_f32_16x16x32_bf16(a1, b1, acc[1][1], 0, 0, 0);
    }
#pragma unroll
    for (int i = 0; i < 2; ++i)
#pragma unroll
        for (int j = 0; j < 2; ++j) {
            int gc = col0 + wn + j * 16 + l16;
            int h = gc >> 4, kk = gc & 15;
#pragma unroll
            for (int r = 0; r < 4; ++r) {
                int gr = row0 + wm + i * 16 + quad * 4 + r;
                if (gr < BN_) Vs[h * (BN_ * 16) + gr * 16 + kk] = f2b(acc[i][j][r]);
            }
        }
}

// k_out: H1 = z + flag.*(VsFlat @ WoutT^T) ; atomics -> accO. grid (313,2)
__global__ __launch_bounds__(256) void k_out(const unsigned short* __restrict__ Vs,
                                             const unsigned short* __restrict__ Bt,
                                             const float* __restrict__ H,
                                             const float* __restrict__ accP,
                                             const float* __restrict__ bnw,
                                             const float* __restrict__ bnb,
                                             const float* __restrict__ flag,
                                             float* __restrict__ H1,
                                             float* __restrict__ accO) {
    __shared__ unsigned short As[64 * LSTR];
    __shared__ unsigned short Bs[64 * LSTR];
    __shared__ float ss_sh[256];
    const int tid = threadIdx.x;
    const int row0 = blockIdx.x * 64, col0 = blockIdx.y * 64;
    make_ss(accP, bnw, bnb, ss_sh, tid);
#pragma unroll
    for (int it = 0; it < 4; ++it) {
        int idx = tid + it * 256;
        int m = idx >> 4, k0 = (idx & 15) << 3;
        int gr = row0 + m;
        uint4 w = make_uint4(0u, 0u, 0u, 0u);
        if (gr < BN_) w = *(const uint4*)(Vs + gr * D_ + k0);
        *(uint4*)&As[m * LSTR + k0] = w;
    }
#pragma unroll
    for (int it = 0; it < 4; ++it) {
        int idx = tid + it * 256;
        int n = idx >> 4, k0 = (idx & 15) << 3;
        *(uint4*)&Bs[n * LSTR + k0] = *(const uint4*)(Bt + (col0 + n) * D_ + k0);
    }
    __syncthreads();
    const int lane = tid & 63, wave = tid >> 6;
    const int l16 = lane & 15, quad = lane >> 4;
    const int wm = (wave >> 1) * 32, wn = (wave & 1) * 32;
    f32x4 acc[2][2] = {};
#pragma unroll
    for (int kb = 0; kb < 128; kb += 32) {
        bf16x8 a0 = *(bf16x8*)&As[(wm + l16) * LSTR + kb + quad * 8];
        bf16x8 a1 = *(bf16x8*)&As[(wm + 16 + l16) * LSTR + kb + quad * 8];
        bf16x8 b0 = *(bf16x8*)&Bs[(wn + l16) * LSTR + kb + quad * 8];
        bf16x8 b1 = *(bf16x8*)&Bs[(wn + 16 + l16) * LSTR + kb + quad * 8];
        acc[0][0] = __builtin_amdgcn_mfma_f32_16x16x32_bf16(a0, b0, acc[0][0], 0, 0, 0);
        acc[0][1] = __builtin_amdgcn_mfma_f32_16x16x32_bf16(a0, b1, acc[0][1], 0, 0, 0);
        acc[1][0] = __builtin_amdgcn_mfma_f32_16x16x32_bf16(a1, b0, acc[1][0], 0, 0, 0);
        acc[1][1] = __builtin_amdgcn_mfma_f32_16x16x32_bf16(a1, b1, acc[1][1], 0, 0, 0);
    }
    __syncthreads();   // LDS reuse for stats
    float* Sred = (float*)As;  // [64][8]
    float* Qred = (float*)Bs;
    const int slot = (wave >> 1) * 4 + quad;
#pragma unroll
    for (int j = 0; j < 2; ++j) {
        int gc = col0 + wn + j * 16 + l16;
        float sc = ss_sh[gc & 127];
        float sh = ss_sh[128 + (gc & 127)];
        float cs = 0.f, cq = 0.f;
#pragma unroll
        for (int i = 0; i < 2; ++i)
#pragma unroll
            for (int r = 0; r < 4; ++r) {
                int gr = row0 + wm + i * 16 + quad * 4 + r;
                if (gr < BN_) {
                    float z = H[gr * D_ + gc] * sc + sh;
                    float o = z + flag[gr] * acc[i][j][r];
                    H1[gr * D_ + gc] = o;
                    cs += o; cq += o * o;
                }
            }
        Sred[(wn + j * 16 + l16) * 8 + slot] = cs;
        Qred[(wn + j * 16 + l16) * 8 + slot] = cq;
    }
    __syncthreads();
    if (tid < 64) {
        float s = 0.f, q = 0.f;
#pragma unroll
        for (int t = 0; t < 8; ++t) { s += Sred[tid * 8 + t]; q += Qred[tid * 8 + t]; }
        atomicAdd(&accO[col0 + tid], s);
        atomicAdd(&accO[128 + col0 + tid], q);
    }
}

// ---------------- fused FF1+FF2 ----------------
// per block: 64 rows. z = BN1(H1) staged bf16 (64x128).
// loop 8 chunks of 64 FF-cols: T_chunk = relu(z@W1T_chunk + b1) -> LDS;
// acc2 += T_chunk @ W2T_kchunk. epilogue: H2 = z + acc2 + b2, stats->accO.
// grid (313), 256 thr.
__global__ __launch_bounds__(256) void k_ff(const float* __restrict__ H1,
                                            const float* __restrict__ accP,
                                            const float* __restrict__ bnw,
                                            const float* __restrict__ bnb,
                                            const unsigned short* __restrict__ W1t,
                                            const float* __restrict__ b1l,
                                            const unsigned short* __restrict__ W2t,
                                            const float* __restrict__ b2l,
                                            float* __restrict__ H2,
                                            float* __restrict__ accO) {
    __shared__ unsigned short As[64 * LSTR];    // z bf16
    __shared__ unsigned short Bs[64 * LSTR];    // W1T chunk
    __shared__ unsigned short B2[128 * B2STR];  // W2T k-chunk
    __shared__ unsigned short Tch[64 * TSTR];   // T chunk bf16
    __shared__ float ss_sh[256];
    const int tid = threadIdx.x;
    const int row0 = blockIdx.x * 64;
    make_ss(accP, bnw, bnb, ss_sh, tid);
    __syncthreads();
    // stage z = BN1(H1) (64x128)
#pragma unroll
    for (int it = 0; it < 4; ++it) {
        int idx = tid + it * 256;
        int m = idx >> 4, k0 = (idx & 15) << 3;
        int gr = row0 + m;
        float v[8];
        if (gr < BN_) {
            f32x4 v0 = *(const f32x4*)(H1 + gr * D_ + k0);
            f32x4 v1 = *(const f32x4*)(H1 + gr * D_ + k0 + 4);
            v[0] = v0.x; v[1] = v0.y; v[2] = v0.z; v[3] = v0.w;
            v[4] = v1.x; v[5] = v1.y; v[6] = v1.z; v[7] = v1.w;
        } else {
#pragma unroll
            for (int j = 0; j < 8; ++j) v[j] = 0.f;
        }
        unsigned int p[4];
#pragma unroll
        for (int j = 0; j < 4; ++j) {
            unsigned short lo = f2b(v[2 * j] * ss_sh[k0 + 2 * j] + ss_sh[128 + k0 + 2 * j]);
            unsigned short hi = f2b(v[2 * j + 1] * ss_sh[k0 + 2 * j + 1] + ss_sh[128 + k0 + 2 * j + 1]);
            p[j] = (unsigned int)lo | ((unsigned int)hi << 16);
        }
        *(uint4*)&As[m * LSTR + k0] = make_uint4(p[0], p[1], p[2], p[3]);
    }
    const int lane = tid & 63, wave = tid >> 6;
    const int l16 = lane & 15, quad = lane >> 4;
    const int wm = (wave >> 1) * 32;            // rows for both GEMMs
    const int wn = (wave & 1) * 32;             // ff1 chunk-local cols
    const int wn2 = (wave & 1) * 64;            // ff2 cols (0 or 64)
    f32x4 acc2[2][4] = {};
    for (int c = 0; c < 8; ++c) {
        const int cb = c * 64;
        __syncthreads();   // As visible / prev chunk's reads done
        // stage W1T chunk: rows cb..cb+63, k 0..127
#pragma unroll
        for (int it = 0; it < 4; ++it) {
            int idx = tid + it * 256;
            int n = idx >> 4, k0 = (idx & 15) << 3;
            *(uint4*)&Bs[n * LSTR + k0] = *(const uint4*)(W1t + (cb + n) * D_ + k0);
        }
        // stage W2T k-chunk: n 0..127, k2 cb..cb+63
#pragma unroll
        for (int it = 0; it < 4; ++it) {
            int idx = tid + it * 256;
            int n = idx >> 3, k0 = (idx & 7) << 3;
            *(uint4*)&B2[n * B2STR + k0] = *(const uint4*)(W2t + n * FF_ + cb + k0);
        }
        __syncthreads();
        // ff1: T_chunk(64x64) = relu(z @ W1chunk^T + b1)
        f32x4 acc1[2][2] = {};
#pragma unroll
        for (int kb = 0; kb < 128; kb += 32) {
            bf16x8 a0 = *(bf16x8*)&As[(wm + l16) * LSTR + kb + quad * 8];
            bf16x8 a1 = *(bf16x8*)&As[(wm + 16 + l16) * LSTR + kb + quad * 8];
            bf16x8 b0 = *(bf16x8*)&Bs[(wn + l16) * LSTR + kb + quad * 8];
            bf16x8 b1 = *(bf16x8*)&Bs[(wn + 16 + l16) * LSTR + kb + quad * 8];
            acc1[0][0] = __builtin_amdgcn_mfma_f32_16x16x32_bf16(a0, b0, acc1[0][0], 0, 0, 0);
            acc1[0][1] = __builtin_amdgcn_mfma_f32_16x16x32_bf16(a0, b1, acc1[0][1], 0, 0, 0);
            acc1[1][0] = __builtin_amdgcn_mfma_f32_16x16x32_bf16(a1, b0, acc1[1][0], 0, 0, 0);
            acc1[1][1] = __builtin_amdgcn_mfma_f32_16x16x32_bf16(a1, b1, acc1[1][1], 0, 0, 0);
        }
#pragma unroll
        for (int j = 0; j < 2; ++j) {
            int lc = wn + j * 16 + l16;
            float bb = b1l[cb + lc];
#pragma unroll
            for (int i = 0; i < 2; ++i)
#pragma unroll
                for (int r = 0; r < 4; ++r)
                    Tch[(wm + i * 16 + quad * 4 + r) * TSTR + lc] =
                        f2b(fmaxf(acc1[i][j][r] + bb, 0.f));
        }
        __syncthreads();
        // ff2 partial: acc2 += T_chunk @ W2chunk^T
#pragma unroll
        for (int kb = 0; kb < 64; kb += 32) {
            bf16x8 a0 = *(bf16x8*)&Tch[(wm + l16) * TSTR + kb + quad * 8];
            bf16x8 a1 = *(bf16x8*)&Tch[(wm + 16 + l16) * TSTR + kb + quad * 8];
#pragma unroll
            for (int j2 = 0; j2 < 4; ++j2) {
                bf16x8 b = *(bf16x8*)&B2[(wn2 + j2 * 16 + l16) * B2STR + kb + quad * 8];
                acc2[0][j2] = __builtin_amdgcn_mfma_f32_16x16x32_bf16(a0, b, acc2[0][j2], 0, 0, 0);
                acc2[1][j2] = __builtin_amdgcn_mfma_f32_16x16x32_bf16(a1, b, acc2[1][j2], 0, 0, 0);
            }
        }
    }
    __syncthreads();
    // epilogue: H2 = H1*sc+sh + acc2 + b2 ; stats
    float* Sred = (float*)As;   // [128][8]
    float* Qred = (float*)Bs;
    const int slot = (wave >> 1) * 4 + quad;
#pragma unroll
    for (int j2 = 0; j2 < 4; ++j2) {
        int gc = wn2 + j2 * 16 + l16;
        float sc = ss_sh[gc], sh = ss_sh[128 + gc], bb = b2l[gc];
        float cs = 0.f, cq = 0.f;
#pragma unroll
        for (int i = 0; i < 2; ++i)
#pragma unroll
            for (int r = 0; r < 4; ++r) {
                int gr = row0 + wm + i * 16 + quad * 4 + r;
                if (gr < BN_) {
                    float o = H1[gr * D_ + gc] * sc + sh + acc2[i][j2][r] + bb;
                    H2[gr * D_ + gc] = o;
                    cs += o; cq += o * o;
                }
            }
        Sred[gc * 8 + slot] = cs;
        Qred[gc * 8 + slot] = cq;
    }
    __syncthreads();
    if (tid < 128) {
        float s = 0.f, q = 0.f;
#pragma unroll
        for (int t = 0; t < 8; ++t) { s += Sred[tid * 8 + t]; q += Qred[tid * 8 + t]; }
        atomicAdd(&accO[tid], s);
        atomicAdd(&accO[128 + tid], q);
    }
}

// final: out = H2*scale + shift
__global__ __launch_bounds__(256) void k_apply(const float4* __restrict__ H2,
                                               const float* __restrict__ accP,
                                               const float* __restrict__ bnw,
                                               const float* __restrict__ bnb,
                                               float4* __restrict__ out) {
    __shared__ float ss_sh[256];
    make_ss(accP, bnw, bnb, ss_sh, threadIdx.x);
    __syncthreads();
    int i = blockIdx.x * 256 + threadIdx.x;
    if (i >= BN_ * D_ / 4) return;
    int c = (i & 31) << 2;
    float4 v = H2[i];
    v.x = v.x * ss_sh[c + 0] + ss_sh[128 + c + 0];
    v.y = v.y * ss_sh[c + 1] + ss_sh[128 + c + 1];
    v.z = v.z * ss_sh[c + 2] + ss_sh[128 + c + 2];
    v.w = v.w * ss_sh[c + 3] + ss_sh[128 + c + 3];
    out[i] = v;
}

// ---------------- launch ----------------

extern "C" void kernel_launch(void* const* d_in, const int* in_sizes, int n_in,
                              void* d_out, int out_size, void* d_ws, size_t ws_size,
                              hipStream_t stream) {
    (void)in_sizes; (void)n_in; (void)out_size; (void)ws_size;
    const float* x    = (const float*)d_in[0];
    const int*   edge = (const int*)d_in[1];
    const float* Wv   = (const float*)d_in[4];
    const float* Wout = (const float*)d_in[5];
    const float* bn1w = (const float*)d_in[6];
    const float* bn1b = (const float*)d_in[7];
    const float* W1   = (const float*)d_in[8];
    const float* b1   = (const float*)d_in[9];
    const float* W2   = (const float*)d_in[10];
    const float* b2   = (const float*)d_in[11];
    const float* bn2w = (const float*)d_in[12];
    const float* bn2b = (const float*)d_in[13];

    float* ws   = (float*)d_ws;
    float* bufA = ws;                    // 2,560,000 (H2)
    float* bufB = ws + 2560000;          // 2,560,000 (H1)
    float* flag = ws + 5120000;          // 20,000
    float* acc6 = ws + 5140000;          // 6 x 256 (bn1/bn2 per layer)
    unsigned short* Vs  = (unsigned short*)(ws + 5141536);   // 2.56M us
    unsigned short* WcT = (unsigned short*)(ws + 6421536);   // 49152 us
    unsigned short* WoT = (unsigned short*)(ws + 6446112);   // 49152 us
    unsigned short* W1T = (unsigned short*)(ws + 6470688);   // 196608 us
    unsigned short* W2T = (unsigned short*)(ws + 6568992);   // 196608 us
    // total ~6.67M floats ~26.7 MiB

    k_prep<<<2005, 256, 0, stream>>>(Wv, Wout, W1, W2, WcT, WoT, W1T, W2T,
                                     flag, acc6);
    k_flag<<<1250, 256, 0, stream>>>(edge + E_, flag);

    for (int l = 0; l < 3; ++l) {
        const float* Hc   = (l == 0) ? x : bufA;
        const float* accP = (l == 0) ? nullptr : acc6 + (2 * l - 1) * 256;
        float* acc1p = acc6 + (2 * l) * 256;       // bn1 stats of this layer
        float* acc2p = acc6 + (2 * l + 1) * 256;   // bn2 stats of this layer
        const float* bw  = bn2w + (l ? (l - 1) * 128 : 0);
        const float* bbv = bn2b + (l ? (l - 1) * 128 : 0);
        k_vs<<<dim3(NBLK, 2), 256, 0, stream>>>(Hc, accP, bw, bbv,
                                                WcT + l * 16384, Vs);
        k_out<<<dim3(NBLK, 2), 256, 0, stream>>>(Vs, WoT + l * 16384, Hc, accP,
                                                 bw, bbv, flag, bufB, acc1p);
        k_ff<<<NBLK, 256, 0, stream>>>(bufB, acc1p, bn1w + l * 128, bn1b + l * 128,
                                       W1T + l * 65536, b1 + l * 512,
                                       W2T + l * 65536, b2 + l * 128, bufA, acc2p);
    }
    k_apply<<<2500, 256, 0, stream>>>((const float4*)bufA, acc6 + 5 * 256,
                                      bn2w + 256, bn2b + 256, (float4*)d_out);
}